// Round 12
// baseline (273.691 us; speedup 1.0000x reference)
//
#include <hip/hip_runtime.h>

// GCN forward: 3x GCNConv (symmetric norm, self-loops) + mean-pool + MLP head.
// R12: agg gather ILP x2 — each thread owns 8 floats (2x float4) of its node's
//      row, so the unroll-4 edge loop keeps 8 independent gathers in flight.
//      (R11: agg32 FETCH=107MB is at the 8-XCD x 12.8MB replication floor, but
//      ran at only 2.3 TB/s vs the 3.6 TB/s the same fabric did in R5 -> MLP-
//      limited, not volume-limited.)

constexpr int EPA1 = 16384;  // edges per level-1 block
constexpr int NPSB = 512;    // nodes per super-bucket
constexpr int PAD1 = 200;    // [blk][sb] metadata row stride

// ---- level 1 histogram: per-block super-bucket counts
__global__ __launch_bounds__(1024) void k_hist1(const int* __restrict__ dst,
        int* __restrict__ cnt1, int nE, int NSB) {
    __shared__ int hist[256];
    int t = threadIdx.x;
    if (t < 256) hist[t] = 0;
    __syncthreads();
    int base = blockIdx.x * EPA1, end = min(base + EPA1, nE);
    for (int e = base + t; e < end; e += 1024)
        atomicAdd(&hist[dst[e] >> 9], 1);  // LDS
    __syncthreads();
    if (t < NSB) cnt1[blockIdx.x * PAD1 + t] = hist[t];
}

// ---- level 1 scan: per-sb exclusive prefix over blocks; emits totals
__global__ __launch_bounds__(256) void k_scan1(const int* __restrict__ cnt1,
        int* __restrict__ po1, int* __restrict__ totals, int NBLK1) {
    __shared__ int sc[256];
    int sb = blockIdx.x, t = threadIdx.x;
    int v = (t < NBLK1) ? cnt1[t * PAD1 + sb] : 0;
    sc[t] = v;
    __syncthreads();
    for (int off = 1; off < 256; off <<= 1) {
        int u = (t >= off) ? sc[t - off] : 0;
        __syncthreads();
        sc[t] += u;
        __syncthreads();
    }
    if (t < NBLK1) po1[t * PAD1 + sb] = sc[t] - v;
    if (t == 255) totals[sb] = sc[255];
}

// ---- level 1 scatter: edges -> super-bucket-major ebuf (packed lnode|src).
__global__ __launch_bounds__(1024) void k_scat1(const int* __restrict__ src,
        const int* __restrict__ dst, const int* __restrict__ po1,
        const int* __restrict__ totals, unsigned* __restrict__ ebuf,
        int nE, int NSB) {
    __shared__ int sc[256], cur[256];
    int t = threadIdx.x, blk = blockIdx.x;
    if (t < 256) sc[t] = (t < NSB) ? totals[t] : 0;
    __syncthreads();
    for (int off = 1; off < 256; off <<= 1) {
        int u = (t >= off && t < 256) ? sc[t - off] : 0;
        __syncthreads();
        if (t < 256) sc[t] += u;
        __syncthreads();
    }
    if (t < NSB) cur[t] = (sc[t] - totals[t]) + po1[blk * PAD1 + t];
    __syncthreads();
    int base = blk * EPA1, end = min(base + EPA1, nE);
    for (int e = base + t; e < end; e += 1024) {
        int s = src[e], d = dst[e];
        int pos = atomicAdd(&cur[d >> 9], 1);  // LDS
        ebuf[pos] = ((unsigned)(d & 511) << 17) | (unsigned)s;  // ~334B segments
    }
}

// ---- level 2: per-sb contiguous counting sort by (node, src-quartile)
__global__ __launch_bounds__(512) void k_sort2(const unsigned* __restrict__ ebuf,
        const int* __restrict__ totals, int* __restrict__ col,
        int* __restrict__ start, float* __restrict__ dinv,
        unsigned* __restrict__ poff, int n, int qsz, int NSB) {
    __shared__ int sc[256];
    __shared__ int hist4[2048], cur4[2048], excl[512];
    int b = blockIdx.x, t = threadIdx.x;
    if (t < 256) sc[t] = (t < NSB) ? totals[t] : 0;
    __syncthreads();
    for (int off = 1; off < 256; off <<= 1) {
        int u = (t >= off && t < 256) ? sc[t - off] : 0;
        __syncthreads();
        if (t < 256) sc[t] += u;
        __syncthreads();
    }
    int eend = sc[b], ebase = eend - totals[b];
    hist4[t] = 0; hist4[t + 512] = 0; hist4[t + 1024] = 0; hist4[t + 1536] = 0;
    __syncthreads();
    for (int e = ebase + t; e < eend; e += 512) {
        unsigned u = ebuf[e];  // contiguous stream
        atomicAdd(&hist4[(u >> 17) * 4 + (int)(u & 0x1FFFFu) / qsz], 1);  // LDS
    }
    __syncthreads();
    int c0 = hist4[t * 4],     c1 = hist4[t * 4 + 1];
    int c2 = hist4[t * 4 + 2], c3 = hist4[t * 4 + 3];
    int v = c0 + c1 + c2 + c3;
    excl[t] = v;
    __syncthreads();
    for (int off = 1; off < 512; off <<= 1) {
        int u = (t >= off) ? excl[t - off] : 0;
        __syncthreads();
        excl[t] += u;
        __syncthreads();
    }
    int sbase = ebase + excl[t] - v;
    cur4[t * 4]     = sbase;
    cur4[t * 4 + 1] = sbase + c0;
    cur4[t * 4 + 2] = sbase + c0 + c1;
    cur4[t * 4 + 3] = sbase + c0 + c1 + c2;
    int node = (b << 9) + t;
    if (node < n) {
        start[node] = sbase;
        dinv[node] = rsqrtf((float)(v + 1));
        poff[node] = (unsigned)c0 | ((unsigned)c1 << 8) |
                     ((unsigned)c2 << 16) | ((unsigned)c3 << 24);
    }
    __syncthreads();
    for (int e = ebase + t; e < eend; e += 512) {
        unsigned u = ebuf[e];  // L2-hot (read in pass 1)
        int s = (int)(u & 0x1FFFFu);
        int pos = atomicAdd(&cur4[(u >> 17) * 4 + s / qsz], 1);  // LDS
        col[pos] = s;  // ~65KB window
    }
}

// ---- fused aggregation, 8 floats (2x float4) per thread for gather ILP.
//   EPI 0: out = dinv[i]*total ; EPI 1: out = dinv[i]*relu(dinv[i]*total + b)
template <int F, int EPI>
__global__ void k_aggf(const float* __restrict__ T, const int* __restrict__ start,
                       const unsigned* __restrict__ poff, const int* __restrict__ col,
                       const float* __restrict__ dinv, const float* __restrict__ bias,
                       float* __restrict__ out, int n) {
    constexpr int TPN = F / 8;       // threads per node (8 floats each)
    constexpr int RS  = F / 4;       // float4s per row
    int idx = blockIdx.x * blockDim.x + threadIdx.x;
    int i = idx / TPN;
    int q = idx % TPN;               // float4 pair index
    if (i >= n) return;
    unsigned pk = poff[i];
    int base = start[i];
    const float4* T4 = (const float4*)T;
    size_t rq = (size_t)i * RS + 2 * q;
    float4 accA = T4[rq], accB = T4[rq + 1];  // self term
    #pragma unroll
    for (int p = 0; p < 4; ++p) {
        int len = (int)((pk >> (8 * p)) & 255u);
        int k = 0;
        for (; k + 4 <= len; k += 4) {
            int s0 = col[base + k],     s1 = col[base + k + 1];
            int s2 = col[base + k + 2], s3 = col[base + k + 3];
            size_t r0 = (size_t)s0 * RS + 2 * q, r1 = (size_t)s1 * RS + 2 * q;
            size_t r2 = (size_t)s2 * RS + 2 * q, r3 = (size_t)s3 * RS + 2 * q;
            float4 a0 = T4[r0], b0 = T4[r0 + 1];
            float4 a1 = T4[r1], b1 = T4[r1 + 1];
            float4 a2 = T4[r2], b2 = T4[r2 + 1];
            float4 a3 = T4[r3], b3 = T4[r3 + 1];
            accA.x += a0.x + a1.x + a2.x + a3.x;
            accA.y += a0.y + a1.y + a2.y + a3.y;
            accA.z += a0.z + a1.z + a2.z + a3.z;
            accA.w += a0.w + a1.w + a2.w + a3.w;
            accB.x += b0.x + b1.x + b2.x + b3.x;
            accB.y += b0.y + b1.y + b2.y + b3.y;
            accB.z += b0.z + b1.z + b2.z + b3.z;
            accB.w += b0.w + b1.w + b2.w + b3.w;
        }
        for (; k < len; ++k) {
            size_t r = (size_t)col[base + k] * RS + 2 * q;
            float4 a = T4[r], b = T4[r + 1];
            accA.x += a.x; accA.y += a.y; accA.z += a.z; accA.w += a.w;
            accB.x += b.x; accB.y += b.y; accB.z += b.z; accB.w += b.w;
        }
        base += len;
    }
    float d = dinv[i];
    float4 oA, oB;
    if (EPI == 0) {
        oA.x = d * accA.x; oA.y = d * accA.y; oA.z = d * accA.z; oA.w = d * accA.w;
        oB.x = d * accB.x; oB.y = d * accB.y; oB.z = d * accB.z; oB.w = d * accB.w;
    } else {
        float4 bA = ((const float4*)bias)[2 * q];
        float4 bB = ((const float4*)bias)[2 * q + 1];
        oA.x = d * fmaxf(d * accA.x + bA.x, 0.0f);
        oA.y = d * fmaxf(d * accA.y + bA.y, 0.0f);
        oA.z = d * fmaxf(d * accA.z + bA.z, 0.0f);
        oA.w = d * fmaxf(d * accA.w + bA.w, 0.0f);
        oB.x = d * fmaxf(d * accB.x + bB.x, 0.0f);
        oB.y = d * fmaxf(d * accB.y + bB.y, 0.0f);
        oB.z = d * fmaxf(d * accB.z + bB.z, 0.0f);
        oB.w = d * fmaxf(d * accB.w + bB.w, 0.0f);
    }
    ((float4*)out)[rq] = oA;
    ((float4*)out)[rq + 1] = oB;
}

// ---- mm1: Pd1 = dinv * (x @ W1), K=128 F=16. LDS-tiled.
__global__ __launch_bounds__(256) void k_mm1(const float4* __restrict__ X4,
        const float4* __restrict__ W4, const float* __restrict__ dinv,
        float* __restrict__ out, int n) {
    __shared__ float4 xs[64 * 32];
    __shared__ float4 ws[512];
    int t = threadIdx.x;
    int nb = blockIdx.x * 64;
    ws[t] = W4[t]; ws[t + 256] = W4[t + 256];
    int lim = min(64, n - nb);
    #pragma unroll
    for (int it = 0; it < 8; ++it) {
        int idx = it * 256 + t;
        if ((idx >> 5) < lim) xs[idx] = X4[(size_t)nb * 32 + idx];
    }
    __syncthreads();
    int lane = t & 63, wv = t >> 6;
    int f = lane & 15, kc = lane >> 4;
    float wcol[32];
    #pragma unroll
    for (int kk = 0; kk < 32; ++kk)
        wcol[kk] = ((const float*)ws)[(kc * 32 + kk) * 16 + f];
    for (int ln = wv * 16; ln < wv * 16 + 16; ++ln) {
        if (ln >= lim) break;
        int i = nb + ln;
        float acc = 0.0f;
        #pragma unroll
        for (int j = 0; j < 8; ++j) {
            float4 hv = xs[ln * 32 + kc * 8 + j];
            acc += hv.x * wcol[4 * j]     + hv.y * wcol[4 * j + 1]
                 + hv.z * wcol[4 * j + 2] + hv.w * wcol[4 * j + 3];
        }
        acc += __shfl_xor(acc, 16);
        acc += __shfl_xor(acc, 32);
        if (kc == 0) out[(size_t)i * 16 + f] = acc * dinv[i];
    }
}

// ---- mm2: h2d = dinv * relu(a1 @ W2 + b2), K=16 F=32
__global__ void k_mm2(const float* __restrict__ H, const float* __restrict__ W,
                      const float* __restrict__ b, const float* __restrict__ dinv,
                      float* __restrict__ out, int n, int nwaves) {
    int lane = threadIdx.x & 63;
    int wid = (blockIdx.x * blockDim.x + threadIdx.x) >> 6;
    int f = lane & 31, p = lane >> 5;
    float wcol[16];
    #pragma unroll
    for (int k = 0; k < 16; ++k) wcol[k] = W[k * 32 + f];
    float bias = b[f];
    for (int i0 = wid * 2; i0 < n; i0 += nwaves * 2) {
        int i = i0 + p;
        if (i < n) {
            const float4* h4 = (const float4*)(H + (size_t)i * 16);
            float acc = bias;
            #pragma unroll
            for (int j = 0; j < 4; ++j) {
                float4 hv = h4[j];
                acc += hv.x * wcol[j * 4]     + hv.y * wcol[j * 4 + 1]
                     + hv.z * wcol[j * 4 + 2] + hv.w * wcol[j * 4 + 3];
            }
            out[(size_t)i * 32 + f] = fmaxf(acc, 0.0f) * dinv[i];
        }
    }
}

// ---- mm3: h3 = relu(a2 @ W3 + b3), K=32 F=64
__global__ void k_mm3(const float* __restrict__ H, const float* __restrict__ W,
                      const float* __restrict__ b, float* __restrict__ out,
                      int n, int nwaves) {
    int lane = threadIdx.x & 63;
    int wid = (blockIdx.x * blockDim.x + threadIdx.x) >> 6;
    float wcol[32];
    #pragma unroll
    for (int k = 0; k < 32; ++k) wcol[k] = W[k * 64 + lane];
    float bias = b[lane];
    for (int i = wid; i < n; i += nwaves) {
        const float4* h4 = (const float4*)(H + (size_t)i * 32);
        float acc = bias;
        #pragma unroll
        for (int j = 0; j < 8; ++j) {
            float4 hv = h4[j];
            acc += hv.x * wcol[j * 4]     + hv.y * wcol[j * 4 + 1]
                 + hv.z * wcol[j * 4 + 2] + hv.w * wcol[j * 4 + 3];
        }
        out[(size_t)i * 64 + lane] = fmaxf(acc, 0.0f);
    }
}

// ---- fused mean-pool + MLP head: 256 threads per graph (4-way row parallel)
__global__ __launch_bounds__(256) void k_poolhead(const float* __restrict__ h3,
        const int* __restrict__ batch, const float* __restrict__ Wl1,
        const float* __restrict__ bl1, const float* __restrict__ Wl2,
        const float* __restrict__ bl2, float* __restrict__ out, int n) {
    int g = blockIdx.x, t = threadIdx.x;
    int f = t & 63, r = t >> 6;
    __shared__ int sb[2];
    __shared__ float part[4][64];
    __shared__ float mean[64], hid[64];
    if (t < 2) {
        int target = g + t;
        int lo = 0, hi = n;
        while (lo < hi) {
            int mid = (lo + hi) >> 1;
            if (batch[mid] < target) lo = mid + 1; else hi = mid;
        }
        sb[t] = lo;
    }
    __syncthreads();
    int s = sb[0], e = sb[1];
    float acc = 0.0f;
    for (int i = s + r; i < e; i += 4) acc += h3[(size_t)i * 64 + f];
    part[r][f] = acc;
    __syncthreads();
    if (t < 64) {
        float c = fmaxf((float)(e - s), 1.0f);
        mean[t] = (part[0][t] + part[1][t] + part[2][t] + part[3][t]) / c;
    }
    __syncthreads();
    if (t < 64) {
        float a = bl1[t];
        #pragma unroll 8
        for (int k = 0; k < 64; ++k) a += mean[k] * Wl1[k * 64 + t];
        hid[t] = fmaxf(a, 0.0f);
    }
    __syncthreads();
    if (t < 2) {
        float o = bl2[t];
        #pragma unroll 8
        for (int k = 0; k < 64; ++k) o += hid[k] * Wl2[k * 2 + t];
        out[g * 2 + t] = o;
    }
}

extern "C" void kernel_launch(void* const* d_in, const int* in_sizes, int n_in,
                              void* d_out, int out_size, void* d_ws, size_t ws_size,
                              hipStream_t stream) {
    const float* x    = (const float*)d_in[0];
    const int*   ei   = (const int*)d_in[1];
    const int*   batch= (const int*)d_in[2];
    const float* W1   = (const float*)d_in[3];
    const float* b1   = (const float*)d_in[4];
    const float* W2   = (const float*)d_in[5];
    const float* b2   = (const float*)d_in[6];
    const float* W3   = (const float*)d_in[7];
    const float* b3   = (const float*)d_in[8];
    const float* Wl1  = (const float*)d_in[9];
    const float* bl1  = (const float*)d_in[10];
    const float* Wl2  = (const float*)d_in[11];
    const float* bl2  = (const float*)d_in[12];
    float* out = (float*)d_out;

    const int n  = in_sizes[2];      // 100000
    const int nE = in_sizes[1] / 2;  // 3200000
    const int* src = ei;
    const int* dst = ei + nE;

    const int NSB   = (n + NPSB - 1) / NPSB;   // 196 super-buckets (512 nodes)
    const int NBLK1 = (nE + EPA1 - 1) / EPA1;  // 196 level-1 blocks
    const int NG    = 1024;
    const int qsz   = (n + 3) / 4;             // src-quartile size

    char* w = (char*)d_ws;
    auto alloc_f = [&](size_t cnt) { float* p = (float*)w; w += cnt * 4; return p; };
    auto alloc_i = [&](size_t cnt) { int*   p = (int*)w;   w += cnt * 4; return p; };

    float*    dinv   = alloc_f(n);
    int*      start  = alloc_i(n);
    unsigned* poff   = (unsigned*)alloc_i(n);
    int*      cnt1   = alloc_i((size_t)NBLK1 * PAD1);
    int*      po1    = alloc_i((size_t)NBLK1 * PAD1);
    int*      totals = alloc_i(256);
    unsigned* ebuf   = (unsigned*)alloc_i(nE);   // 12.8 MB
    int*      col    = alloc_i(nE);              // 12.8 MB (contiguous after ebuf)
    float* Pd1 = alloc_f((size_t)n * 16);
    float* h1d = alloc_f((size_t)n * 16);
    float* a1  = alloc_f((size_t)n * 16);
    float* h2d = alloc_f((size_t)n * 32);
    float* a2  = Pd1;            // 32n over Pd1+h1d (both dead by agg3)
    float* h3  = (float*)ebuf;   // 64n over ebuf+col (dead by mm3)

    const int B = 256;
    auto g = [&](long long t) { return (int)((t + B - 1) / B); };
    const int MMBLK = 1024;
    const int NW = MMBLK * (B / 64);

    // ---- CSR build: two-level radix, zero global atomics
    k_hist1<<<NBLK1, 1024, 0, stream>>>(dst, cnt1, nE, NSB);
    k_scan1<<<NSB, 256, 0, stream>>>(cnt1, po1, totals, NBLK1);
    k_scat1<<<NBLK1, 1024, 0, stream>>>(src, dst, po1, totals, ebuf, nE, NSB);
    k_sort2<<<NSB, 512, 0, stream>>>(ebuf, totals, col, start, dinv, poff, n, qsz, NSB);

    // ---- layer 1: Pd1 = dinv*(x@W1); h1d = dinv*relu(dinv*Agg(Pd1)+b1)
    k_mm1<<<(n + 63) / 64, 256, 0, stream>>>((const float4*)x, (const float4*)W1,
                                             dinv, Pd1, n);
    k_aggf<16, 1><<<g((long long)n * 2), B, 0, stream>>>(Pd1, start, poff, col, dinv, b1, h1d, n);

    // ---- layer 2: a1 = dinv*Agg(h1d); h2d = dinv*relu(a1@W2+b2)
    k_aggf<16, 0><<<g((long long)n * 2), B, 0, stream>>>(h1d, start, poff, col, dinv, nullptr, a1, n);
    k_mm2<<<MMBLK, B, 0, stream>>>(a1, W2, b2, dinv, h2d, n, NW);

    // ---- layer 3: a2 = dinv*Agg(h2d); h3 = relu(a2@W3+b3)
    k_aggf<32, 0><<<g((long long)n * 4), B, 0, stream>>>(h2d, start, poff, col, dinv, nullptr, a2, n);
    k_mm3<<<MMBLK, B, 0, stream>>>(a2, W3, b3, h3, n, NW);

    // ---- fused mean-pool + head (no atomics; batch is sorted)
    k_poolhead<<<NG, 256, 0, stream>>>(h3, batch, Wl1, bl1, Wl2, bl2, out, n);
}

// Round 13
// 272.389 us; speedup vs baseline: 1.0048x; 1.0048x over previous
//
#include <hip/hip_runtime.h>

// GCN forward: 3x GCNConv (symmetric norm, self-loops) + mean-pool + MLP head.
// R13: revert agg to R11 shape (TPN=F/4; R12's ILP x2 regressed: +17% FETCH,
//      -12% occupancy), and flatten the quartile loop into one unroll-8 run —
//      col is already quartile-sorted, so the access order (and L2 phasing) is
//      identical with less branch/loop overhead.

constexpr int EPA1 = 16384;  // edges per level-1 block
constexpr int NPSB = 512;    // nodes per super-bucket
constexpr int PAD1 = 200;    // [blk][sb] metadata row stride

// ---- level 1 histogram: per-block super-bucket counts
__global__ __launch_bounds__(1024) void k_hist1(const int* __restrict__ dst,
        int* __restrict__ cnt1, int nE, int NSB) {
    __shared__ int hist[256];
    int t = threadIdx.x;
    if (t < 256) hist[t] = 0;
    __syncthreads();
    int base = blockIdx.x * EPA1, end = min(base + EPA1, nE);
    for (int e = base + t; e < end; e += 1024)
        atomicAdd(&hist[dst[e] >> 9], 1);  // LDS
    __syncthreads();
    if (t < NSB) cnt1[blockIdx.x * PAD1 + t] = hist[t];
}

// ---- level 1 scan: per-sb exclusive prefix over blocks; emits totals
__global__ __launch_bounds__(256) void k_scan1(const int* __restrict__ cnt1,
        int* __restrict__ po1, int* __restrict__ totals, int NBLK1) {
    __shared__ int sc[256];
    int sb = blockIdx.x, t = threadIdx.x;
    int v = (t < NBLK1) ? cnt1[t * PAD1 + sb] : 0;
    sc[t] = v;
    __syncthreads();
    for (int off = 1; off < 256; off <<= 1) {
        int u = (t >= off) ? sc[t - off] : 0;
        __syncthreads();
        sc[t] += u;
        __syncthreads();
    }
    if (t < NBLK1) po1[t * PAD1 + sb] = sc[t] - v;
    if (t == 255) totals[sb] = sc[255];
}

// ---- level 1 scatter: edges -> super-bucket-major ebuf (packed lnode|src).
__global__ __launch_bounds__(1024) void k_scat1(const int* __restrict__ src,
        const int* __restrict__ dst, const int* __restrict__ po1,
        const int* __restrict__ totals, unsigned* __restrict__ ebuf,
        int nE, int NSB) {
    __shared__ int sc[256], cur[256];
    int t = threadIdx.x, blk = blockIdx.x;
    if (t < 256) sc[t] = (t < NSB) ? totals[t] : 0;
    __syncthreads();
    for (int off = 1; off < 256; off <<= 1) {
        int u = (t >= off && t < 256) ? sc[t - off] : 0;
        __syncthreads();
        if (t < 256) sc[t] += u;
        __syncthreads();
    }
    if (t < NSB) cur[t] = (sc[t] - totals[t]) + po1[blk * PAD1 + t];
    __syncthreads();
    int base = blk * EPA1, end = min(base + EPA1, nE);
    for (int e = base + t; e < end; e += 1024) {
        int s = src[e], d = dst[e];
        int pos = atomicAdd(&cur[d >> 9], 1);  // LDS
        ebuf[pos] = ((unsigned)(d & 511) << 17) | (unsigned)s;  // ~334B segments
    }
}

// ---- level 2: per-sb contiguous counting sort by (node, src-quartile)
__global__ __launch_bounds__(512) void k_sort2(const unsigned* __restrict__ ebuf,
        const int* __restrict__ totals, int* __restrict__ col,
        int* __restrict__ start, float* __restrict__ dinv,
        unsigned* __restrict__ poff, int n, int qsz, int NSB) {
    __shared__ int sc[256];
    __shared__ int hist4[2048], cur4[2048], excl[512];
    int b = blockIdx.x, t = threadIdx.x;
    if (t < 256) sc[t] = (t < NSB) ? totals[t] : 0;
    __syncthreads();
    for (int off = 1; off < 256; off <<= 1) {
        int u = (t >= off && t < 256) ? sc[t - off] : 0;
        __syncthreads();
        if (t < 256) sc[t] += u;
        __syncthreads();
    }
    int eend = sc[b], ebase = eend - totals[b];
    hist4[t] = 0; hist4[t + 512] = 0; hist4[t + 1024] = 0; hist4[t + 1536] = 0;
    __syncthreads();
    for (int e = ebase + t; e < eend; e += 512) {
        unsigned u = ebuf[e];  // contiguous stream
        atomicAdd(&hist4[(u >> 17) * 4 + (int)(u & 0x1FFFFu) / qsz], 1);  // LDS
    }
    __syncthreads();
    int c0 = hist4[t * 4],     c1 = hist4[t * 4 + 1];
    int c2 = hist4[t * 4 + 2], c3 = hist4[t * 4 + 3];
    int v = c0 + c1 + c2 + c3;
    excl[t] = v;
    __syncthreads();
    for (int off = 1; off < 512; off <<= 1) {
        int u = (t >= off) ? excl[t - off] : 0;
        __syncthreads();
        excl[t] += u;
        __syncthreads();
    }
    int sbase = ebase + excl[t] - v;
    cur4[t * 4]     = sbase;
    cur4[t * 4 + 1] = sbase + c0;
    cur4[t * 4 + 2] = sbase + c0 + c1;
    cur4[t * 4 + 3] = sbase + c0 + c1 + c2;
    int node = (b << 9) + t;
    if (node < n) {
        start[node] = sbase;
        dinv[node] = rsqrtf((float)(v + 1));
        poff[node] = (unsigned)c0 | ((unsigned)c1 << 8) |
                     ((unsigned)c2 << 16) | ((unsigned)c3 << 24);
    }
    __syncthreads();
    for (int e = ebase + t; e < eend; e += 512) {
        unsigned u = ebuf[e];  // L2-hot (read in pass 1)
        int s = (int)(u & 0x1FFFFu);
        int pos = atomicAdd(&cur4[(u >> 17) * 4 + s / qsz], 1);  // LDS
        col[pos] = s;  // ~65KB window
    }
}

// ---- fused aggregation, flat unroll-8 loop (col is quartile-sorted already).
//   EPI 0: out = dinv[i]*total ; EPI 1: out = dinv[i]*relu(dinv[i]*total + b)
template <int F, int EPI>
__global__ void k_aggf(const float* __restrict__ T, const int* __restrict__ start,
                       const unsigned* __restrict__ poff, const int* __restrict__ col,
                       const float* __restrict__ dinv, const float* __restrict__ bias,
                       float* __restrict__ out, int n) {
    constexpr int TPN = F / 4;
    int idx = blockIdx.x * blockDim.x + threadIdx.x;
    int i = idx / TPN;
    int q = idx % TPN;
    if (i >= n) return;
    unsigned pk = poff[i];
    int len = (int)(pk & 255u) + (int)((pk >> 8) & 255u)
            + (int)((pk >> 16) & 255u) + (int)(pk >> 24);
    int base = start[i];
    const float4* T4 = (const float4*)T;
    float4 acc = T4[(size_t)i * TPN + q];  // self term
    int k = 0;
    for (; k + 8 <= len; k += 8) {
        int s0 = col[base + k],     s1 = col[base + k + 1];
        int s2 = col[base + k + 2], s3 = col[base + k + 3];
        int s4 = col[base + k + 4], s5 = col[base + k + 5];
        int s6 = col[base + k + 6], s7 = col[base + k + 7];
        float4 v0 = T4[(size_t)s0 * TPN + q];
        float4 v1 = T4[(size_t)s1 * TPN + q];
        float4 v2 = T4[(size_t)s2 * TPN + q];
        float4 v3 = T4[(size_t)s3 * TPN + q];
        float4 v4 = T4[(size_t)s4 * TPN + q];
        float4 v5 = T4[(size_t)s5 * TPN + q];
        float4 v6 = T4[(size_t)s6 * TPN + q];
        float4 v7 = T4[(size_t)s7 * TPN + q];
        acc.x += (v0.x + v1.x + v2.x + v3.x) + (v4.x + v5.x + v6.x + v7.x);
        acc.y += (v0.y + v1.y + v2.y + v3.y) + (v4.y + v5.y + v6.y + v7.y);
        acc.z += (v0.z + v1.z + v2.z + v3.z) + (v4.z + v5.z + v6.z + v7.z);
        acc.w += (v0.w + v1.w + v2.w + v3.w) + (v4.w + v5.w + v6.w + v7.w);
    }
    for (; k + 4 <= len; k += 4) {
        int s0 = col[base + k],     s1 = col[base + k + 1];
        int s2 = col[base + k + 2], s3 = col[base + k + 3];
        float4 v0 = T4[(size_t)s0 * TPN + q];
        float4 v1 = T4[(size_t)s1 * TPN + q];
        float4 v2 = T4[(size_t)s2 * TPN + q];
        float4 v3 = T4[(size_t)s3 * TPN + q];
        acc.x += v0.x + v1.x + v2.x + v3.x;
        acc.y += v0.y + v1.y + v2.y + v3.y;
        acc.z += v0.z + v1.z + v2.z + v3.z;
        acc.w += v0.w + v1.w + v2.w + v3.w;
    }
    for (; k < len; ++k) {
        float4 v = T4[(size_t)col[base + k] * TPN + q];
        acc.x += v.x; acc.y += v.y; acc.z += v.z; acc.w += v.w;
    }
    float d = dinv[i];
    float4 o;
    if (EPI == 0) {
        o.x = d * acc.x; o.y = d * acc.y; o.z = d * acc.z; o.w = d * acc.w;
    } else {
        float4 b = ((const float4*)bias)[q];
        o.x = d * fmaxf(d * acc.x + b.x, 0.0f);
        o.y = d * fmaxf(d * acc.y + b.y, 0.0f);
        o.z = d * fmaxf(d * acc.z + b.z, 0.0f);
        o.w = d * fmaxf(d * acc.w + b.w, 0.0f);
    }
    ((float4*)out)[(size_t)i * TPN + q] = o;
}

// ---- mm1: Pd1 = dinv * (x @ W1), K=128 F=16. LDS-tiled.
__global__ __launch_bounds__(256) void k_mm1(const float4* __restrict__ X4,
        const float4* __restrict__ W4, const float* __restrict__ dinv,
        float* __restrict__ out, int n) {
    __shared__ float4 xs[64 * 32];
    __shared__ float4 ws[512];
    int t = threadIdx.x;
    int nb = blockIdx.x * 64;
    ws[t] = W4[t]; ws[t + 256] = W4[t + 256];
    int lim = min(64, n - nb);
    #pragma unroll
    for (int it = 0; it < 8; ++it) {
        int idx = it * 256 + t;
        if ((idx >> 5) < lim) xs[idx] = X4[(size_t)nb * 32 + idx];
    }
    __syncthreads();
    int lane = t & 63, wv = t >> 6;
    int f = lane & 15, kc = lane >> 4;
    float wcol[32];
    #pragma unroll
    for (int kk = 0; kk < 32; ++kk)
        wcol[kk] = ((const float*)ws)[(kc * 32 + kk) * 16 + f];
    for (int ln = wv * 16; ln < wv * 16 + 16; ++ln) {
        if (ln >= lim) break;
        int i = nb + ln;
        float acc = 0.0f;
        #pragma unroll
        for (int j = 0; j < 8; ++j) {
            float4 hv = xs[ln * 32 + kc * 8 + j];
            acc += hv.x * wcol[4 * j]     + hv.y * wcol[4 * j + 1]
                 + hv.z * wcol[4 * j + 2] + hv.w * wcol[4 * j + 3];
        }
        acc += __shfl_xor(acc, 16);
        acc += __shfl_xor(acc, 32);
        if (kc == 0) out[(size_t)i * 16 + f] = acc * dinv[i];
    }
}

// ---- mm2: h2d = dinv * relu(a1 @ W2 + b2), K=16 F=32
__global__ void k_mm2(const float* __restrict__ H, const float* __restrict__ W,
                      const float* __restrict__ b, const float* __restrict__ dinv,
                      float* __restrict__ out, int n, int nwaves) {
    int lane = threadIdx.x & 63;
    int wid = (blockIdx.x * blockDim.x + threadIdx.x) >> 6;
    int f = lane & 31, p = lane >> 5;
    float wcol[16];
    #pragma unroll
    for (int k = 0; k < 16; ++k) wcol[k] = W[k * 32 + f];
    float bias = b[f];
    for (int i0 = wid * 2; i0 < n; i0 += nwaves * 2) {
        int i = i0 + p;
        if (i < n) {
            const float4* h4 = (const float4*)(H + (size_t)i * 16);
            float acc = bias;
            #pragma unroll
            for (int j = 0; j < 4; ++j) {
                float4 hv = h4[j];
                acc += hv.x * wcol[j * 4]     + hv.y * wcol[j * 4 + 1]
                     + hv.z * wcol[j * 4 + 2] + hv.w * wcol[j * 4 + 3];
            }
            out[(size_t)i * 32 + f] = fmaxf(acc, 0.0f) * dinv[i];
        }
    }
}

// ---- mm3: h3 = relu(a2 @ W3 + b3), K=32 F=64
__global__ void k_mm3(const float* __restrict__ H, const float* __restrict__ W,
                      const float* __restrict__ b, float* __restrict__ out,
                      int n, int nwaves) {
    int lane = threadIdx.x & 63;
    int wid = (blockIdx.x * blockDim.x + threadIdx.x) >> 6;
    float wcol[32];
    #pragma unroll
    for (int k = 0; k < 32; ++k) wcol[k] = W[k * 64 + lane];
    float bias = b[lane];
    for (int i = wid; i < n; i += nwaves) {
        const float4* h4 = (const float4*)(H + (size_t)i * 32);
        float acc = bias;
        #pragma unroll
        for (int j = 0; j < 8; ++j) {
            float4 hv = h4[j];
            acc += hv.x * wcol[j * 4]     + hv.y * wcol[j * 4 + 1]
                 + hv.z * wcol[j * 4 + 2] + hv.w * wcol[j * 4 + 3];
        }
        out[(size_t)i * 64 + lane] = fmaxf(acc, 0.0f);
    }
}

// ---- fused mean-pool + MLP head: 256 threads per graph (4-way row parallel)
__global__ __launch_bounds__(256) void k_poolhead(const float* __restrict__ h3,
        const int* __restrict__ batch, const float* __restrict__ Wl1,
        const float* __restrict__ bl1, const float* __restrict__ Wl2,
        const float* __restrict__ bl2, float* __restrict__ out, int n) {
    int g = blockIdx.x, t = threadIdx.x;
    int f = t & 63, r = t >> 6;
    __shared__ int sb[2];
    __shared__ float part[4][64];
    __shared__ float mean[64], hid[64];
    if (t < 2) {
        int target = g + t;
        int lo = 0, hi = n;
        while (lo < hi) {
            int mid = (lo + hi) >> 1;
            if (batch[mid] < target) lo = mid + 1; else hi = mid;
        }
        sb[t] = lo;
    }
    __syncthreads();
    int s = sb[0], e = sb[1];
    float acc = 0.0f;
    for (int i = s + r; i < e; i += 4) acc += h3[(size_t)i * 64 + f];
    part[r][f] = acc;
    __syncthreads();
    if (t < 64) {
        float c = fmaxf((float)(e - s), 1.0f);
        mean[t] = (part[0][t] + part[1][t] + part[2][t] + part[3][t]) / c;
    }
    __syncthreads();
    if (t < 64) {
        float a = bl1[t];
        #pragma unroll 8
        for (int k = 0; k < 64; ++k) a += mean[k] * Wl1[k * 64 + t];
        hid[t] = fmaxf(a, 0.0f);
    }
    __syncthreads();
    if (t < 2) {
        float o = bl2[t];
        #pragma unroll 8
        for (int k = 0; k < 64; ++k) o += hid[k] * Wl2[k * 2 + t];
        out[g * 2 + t] = o;
    }
}

extern "C" void kernel_launch(void* const* d_in, const int* in_sizes, int n_in,
                              void* d_out, int out_size, void* d_ws, size_t ws_size,
                              hipStream_t stream) {
    const float* x    = (const float*)d_in[0];
    const int*   ei   = (const int*)d_in[1];
    const int*   batch= (const int*)d_in[2];
    const float* W1   = (const float*)d_in[3];
    const float* b1   = (const float*)d_in[4];
    const float* W2   = (const float*)d_in[5];
    const float* b2   = (const float*)d_in[6];
    const float* W3   = (const float*)d_in[7];
    const float* b3   = (const float*)d_in[8];
    const float* Wl1  = (const float*)d_in[9];
    const float* bl1  = (const float*)d_in[10];
    const float* Wl2  = (const float*)d_in[11];
    const float* bl2  = (const float*)d_in[12];
    float* out = (float*)d_out;

    const int n  = in_sizes[2];      // 100000
    const int nE = in_sizes[1] / 2;  // 3200000
    const int* src = ei;
    const int* dst = ei + nE;

    const int NSB   = (n + NPSB - 1) / NPSB;   // 196 super-buckets (512 nodes)
    const int NBLK1 = (nE + EPA1 - 1) / EPA1;  // 196 level-1 blocks
    const int NG    = 1024;
    const int qsz   = (n + 3) / 4;             // src-quartile size

    char* w = (char*)d_ws;
    auto alloc_f = [&](size_t cnt) { float* p = (float*)w; w += cnt * 4; return p; };
    auto alloc_i = [&](size_t cnt) { int*   p = (int*)w;   w += cnt * 4; return p; };

    float*    dinv   = alloc_f(n);
    int*      start  = alloc_i(n);
    unsigned* poff   = (unsigned*)alloc_i(n);
    int*      cnt1   = alloc_i((size_t)NBLK1 * PAD1);
    int*      po1    = alloc_i((size_t)NBLK1 * PAD1);
    int*      totals = alloc_i(256);
    unsigned* ebuf   = (unsigned*)alloc_i(nE);   // 12.8 MB
    int*      col    = alloc_i(nE);              // 12.8 MB (contiguous after ebuf)
    float* Pd1 = alloc_f((size_t)n * 16);
    float* h1d = alloc_f((size_t)n * 16);
    float* a1  = alloc_f((size_t)n * 16);
    float* h2d = alloc_f((size_t)n * 32);
    float* a2  = Pd1;            // 32n over Pd1+h1d (both dead by agg3)
    float* h3  = (float*)ebuf;   // 64n over ebuf+col (dead by mm3)

    const int B = 256;
    auto g = [&](long long t) { return (int)((t + B - 1) / B); };
    const int MMBLK = 1024;
    const int NW = MMBLK * (B / 64);

    // ---- CSR build: two-level radix, zero global atomics
    k_hist1<<<NBLK1, 1024, 0, stream>>>(dst, cnt1, nE, NSB);
    k_scan1<<<NSB, 256, 0, stream>>>(cnt1, po1, totals, NBLK1);
    k_scat1<<<NBLK1, 1024, 0, stream>>>(src, dst, po1, totals, ebuf, nE, NSB);
    k_sort2<<<NSB, 512, 0, stream>>>(ebuf, totals, col, start, dinv, poff, n, qsz, NSB);

    // ---- layer 1: Pd1 = dinv*(x@W1); h1d = dinv*relu(dinv*Agg(Pd1)+b1)
    k_mm1<<<(n + 63) / 64, 256, 0, stream>>>((const float4*)x, (const float4*)W1,
                                             dinv, Pd1, n);
    k_aggf<16, 1><<<g((long long)n * 4), B, 0, stream>>>(Pd1, start, poff, col, dinv, b1, h1d, n);

    // ---- layer 2: a1 = dinv*Agg(h1d); h2d = dinv*relu(a1@W2+b2)
    k_aggf<16, 0><<<g((long long)n * 4), B, 0, stream>>>(h1d, start, poff, col, dinv, nullptr, a1, n);
    k_mm2<<<MMBLK, B, 0, stream>>>(a1, W2, b2, dinv, h2d, n, NW);

    // ---- layer 3: a2 = dinv*Agg(h2d); h3 = relu(a2@W3+b3)
    k_aggf<32, 0><<<g((long long)n * 8), B, 0, stream>>>(h2d, start, poff, col, dinv, nullptr, a2, n);
    k_mm3<<<MMBLK, B, 0, stream>>>(a2, W3, b3, h3, n, NW);

    // ---- fused mean-pool + head (no atomics; batch is sorted)
    k_poolhead<<<NG, 256, 0, stream>>>(h3, batch, Wl1, bl1, Wl2, bl2, out, n);
}

// Round 14
// 238.287 us; speedup vs baseline: 1.1486x; 1.1431x over previous
//
#include <hip/hip_runtime.h>

// GCN forward: 3x GCNConv (symmetric norm, self-loops) + mean-pool + MLP head.
// R14: R11 base (best: 257us) + matmul-into-agg fusion. agg is latency-bound
//      (VALUBusy 11%, miss-queue limited — R11/R12/R13 all ~47-50us regardless
//      of rate/volume tradeoff), so the dense W2/W3 matmuls ride free in the
//      epilogue via intra-group shfl. Kills a1/a2 buffers, mm2/mm3 kernels.

constexpr int EPA1 = 16384;  // edges per level-1 block
constexpr int NPSB = 512;    // nodes per super-bucket
constexpr int PAD1 = 200;    // [blk][sb] metadata row stride

// ---- level 1 histogram: per-block super-bucket counts
__global__ __launch_bounds__(1024) void k_hist1(const int* __restrict__ dst,
        int* __restrict__ cnt1, int nE, int NSB) {
    __shared__ int hist[256];
    int t = threadIdx.x;
    if (t < 256) hist[t] = 0;
    __syncthreads();
    int base = blockIdx.x * EPA1, end = min(base + EPA1, nE);
    for (int e = base + t; e < end; e += 1024)
        atomicAdd(&hist[dst[e] >> 9], 1);  // LDS
    __syncthreads();
    if (t < NSB) cnt1[blockIdx.x * PAD1 + t] = hist[t];
}

// ---- level 1 scan: per-sb exclusive prefix over blocks; emits totals
__global__ __launch_bounds__(256) void k_scan1(const int* __restrict__ cnt1,
        int* __restrict__ po1, int* __restrict__ totals, int NBLK1) {
    __shared__ int sc[256];
    int sb = blockIdx.x, t = threadIdx.x;
    int v = (t < NBLK1) ? cnt1[t * PAD1 + sb] : 0;
    sc[t] = v;
    __syncthreads();
    for (int off = 1; off < 256; off <<= 1) {
        int u = (t >= off) ? sc[t - off] : 0;
        __syncthreads();
        sc[t] += u;
        __syncthreads();
    }
    if (t < NBLK1) po1[t * PAD1 + sb] = sc[t] - v;
    if (t == 255) totals[sb] = sc[255];
}

// ---- level 1 scatter: edges -> super-bucket-major ebuf (packed lnode|src).
__global__ __launch_bounds__(1024) void k_scat1(const int* __restrict__ src,
        const int* __restrict__ dst, const int* __restrict__ po1,
        const int* __restrict__ totals, unsigned* __restrict__ ebuf,
        int nE, int NSB) {
    __shared__ int sc[256], cur[256];
    int t = threadIdx.x, blk = blockIdx.x;
    if (t < 256) sc[t] = (t < NSB) ? totals[t] : 0;
    __syncthreads();
    for (int off = 1; off < 256; off <<= 1) {
        int u = (t >= off && t < 256) ? sc[t - off] : 0;
        __syncthreads();
        if (t < 256) sc[t] += u;
        __syncthreads();
    }
    if (t < NSB) cur[t] = (sc[t] - totals[t]) + po1[blk * PAD1 + t];
    __syncthreads();
    int base = blk * EPA1, end = min(base + EPA1, nE);
    for (int e = base + t; e < end; e += 1024) {
        int s = src[e], d = dst[e];
        int pos = atomicAdd(&cur[d >> 9], 1);  // LDS
        ebuf[pos] = ((unsigned)(d & 511) << 17) | (unsigned)s;  // ~334B segments
    }
}

// ---- level 2: per-sb contiguous counting sort by (node, src-quartile)
__global__ __launch_bounds__(512) void k_sort2(const unsigned* __restrict__ ebuf,
        const int* __restrict__ totals, int* __restrict__ col,
        int* __restrict__ start, float* __restrict__ dinv,
        unsigned* __restrict__ poff, int n, int qsz, int NSB) {
    __shared__ int sc[256];
    __shared__ int hist4[2048], cur4[2048], excl[512];
    int b = blockIdx.x, t = threadIdx.x;
    if (t < 256) sc[t] = (t < NSB) ? totals[t] : 0;
    __syncthreads();
    for (int off = 1; off < 256; off <<= 1) {
        int u = (t >= off && t < 256) ? sc[t - off] : 0;
        __syncthreads();
        if (t < 256) sc[t] += u;
        __syncthreads();
    }
    int eend = sc[b], ebase = eend - totals[b];
    hist4[t] = 0; hist4[t + 512] = 0; hist4[t + 1024] = 0; hist4[t + 1536] = 0;
    __syncthreads();
    for (int e = ebase + t; e < eend; e += 512) {
        unsigned u = ebuf[e];  // contiguous stream
        atomicAdd(&hist4[(u >> 17) * 4 + (int)(u & 0x1FFFFu) / qsz], 1);  // LDS
    }
    __syncthreads();
    int c0 = hist4[t * 4],     c1 = hist4[t * 4 + 1];
    int c2 = hist4[t * 4 + 2], c3 = hist4[t * 4 + 3];
    int v = c0 + c1 + c2 + c3;
    excl[t] = v;
    __syncthreads();
    for (int off = 1; off < 512; off <<= 1) {
        int u = (t >= off) ? excl[t - off] : 0;
        __syncthreads();
        excl[t] += u;
        __syncthreads();
    }
    int sbase = ebase + excl[t] - v;
    cur4[t * 4]     = sbase;
    cur4[t * 4 + 1] = sbase + c0;
    cur4[t * 4 + 2] = sbase + c0 + c1;
    cur4[t * 4 + 3] = sbase + c0 + c1 + c2;
    int node = (b << 9) + t;
    if (node < n) {
        start[node] = sbase;
        dinv[node] = rsqrtf((float)(v + 1));
        poff[node] = (unsigned)c0 | ((unsigned)c1 << 8) |
                     ((unsigned)c2 << 16) | ((unsigned)c3 << 24);
    }
    __syncthreads();
    for (int e = ebase + t; e < eend; e += 512) {
        unsigned u = ebuf[e];  // L2-hot (read in pass 1)
        int s = (int)(u & 0x1FFFFu);
        int pos = atomicAdd(&cur4[(u >> 17) * 4 + s / qsz], 1);  // LDS
        col[pos] = s;  // ~65KB window
    }
}

// ---- shared gather body: quartile loop, register accumulator (R11 shape)
template <int TPN>
__device__ __forceinline__ float4 agg_gather(const float4* __restrict__ T4,
        const int* __restrict__ col, int base, unsigned pk, int q, size_t selfIdx) {
    float4 acc = T4[selfIdx];  // self term
    #pragma unroll
    for (int p = 0; p < 4; ++p) {
        int len = (int)((pk >> (8 * p)) & 255u);
        int k = 0;
        for (; k + 4 <= len; k += 4) {
            int s0 = col[base + k],     s1 = col[base + k + 1];
            int s2 = col[base + k + 2], s3 = col[base + k + 3];
            float4 v0 = T4[(size_t)s0 * TPN + q];
            float4 v1 = T4[(size_t)s1 * TPN + q];
            float4 v2 = T4[(size_t)s2 * TPN + q];
            float4 v3 = T4[(size_t)s3 * TPN + q];
            acc.x += v0.x + v1.x + v2.x + v3.x;
            acc.y += v0.y + v1.y + v2.y + v3.y;
            acc.z += v0.z + v1.z + v2.z + v3.z;
            acc.w += v0.w + v1.w + v2.w + v3.w;
        }
        for (; k < len; ++k) {
            float4 v = T4[(size_t)col[base + k] * TPN + q];
            acc.x += v.x; acc.y += v.y; acc.z += v.z; acc.w += v.w;
        }
        base += len;
    }
    return acc;
}

// ---- layer-1 agg (F=16, EPI: bias+relu+prescale) — exact R11 form
__global__ void k_aggf16(const float* __restrict__ T, const int* __restrict__ start,
        const unsigned* __restrict__ poff, const int* __restrict__ col,
        const float* __restrict__ dinv, const float* __restrict__ bias,
        float* __restrict__ out, int n) {
    int idx = blockIdx.x * blockDim.x + threadIdx.x;
    int i = idx / 4, q = idx % 4;
    if (i >= n) return;
    float4 acc = agg_gather<4>((const float4*)T, col, start[i], poff[i], q,
                               (size_t)i * 4 + q);
    float d = dinv[i];
    float4 b = ((const float4*)bias)[q];
    float4 o;
    o.x = d * fmaxf(d * acc.x + b.x, 0.0f);
    o.y = d * fmaxf(d * acc.y + b.y, 0.0f);
    o.z = d * fmaxf(d * acc.z + b.z, 0.0f);
    o.w = d * fmaxf(d * acc.w + b.w, 0.0f);
    ((float4*)out)[(size_t)i * 4 + q] = o;
}

// ---- layer-2 agg fused with mm2: h2d = dinv*relu( (dinv*Agg(h1d)) @ W2 + b2 )
//      TPN=4 lanes hold the 16-wide a1 row; shfl-broadcast + LDS W2.
__global__ __launch_bounds__(256) void k_aggf16_mm2(const float* __restrict__ T,
        const int* __restrict__ start, const unsigned* __restrict__ poff,
        const int* __restrict__ col, const float* __restrict__ dinv,
        const float* __restrict__ W2, const float* __restrict__ b2,
        float* __restrict__ out, int n) {
    __shared__ float sW[16 * 32];
    __shared__ float sB[32];
    int t = threadIdx.x;
    for (int j = t; j < 512; j += 256) sW[j] = W2[j];
    if (t < 32) sB[t] = b2[t];
    __syncthreads();
    int idx = blockIdx.x * blockDim.x + t;
    int i = idx / 4, q = idx % 4;
    if (i >= n) return;
    float4 acc = agg_gather<4>((const float4*)T, col, start[i], poff[i], q,
                               (size_t)i * 4 + q);
    float d = dinv[i];
    acc.x *= d; acc.y *= d; acc.z *= d; acc.w *= d;  // a1 fragment
    int lane = t & 63;
    int gbase = lane & ~3;  // 4-lane group base
    float h[8];
    #pragma unroll
    for (int o = 0; o < 8; ++o) h[o] = sB[q * 8 + o];
    #pragma unroll
    for (int j = 0; j < 4; ++j) {
        float ax = __shfl(acc.x, gbase + j);
        float ay = __shfl(acc.y, gbase + j);
        float az = __shfl(acc.z, gbase + j);
        float aw = __shfl(acc.w, gbase + j);
        const float* w0 = &sW[(4 * j) * 32 + q * 8];
        #pragma unroll
        for (int o = 0; o < 8; ++o) {
            h[o] += ax * w0[o] + ay * w0[32 + o] + az * w0[64 + o] + aw * w0[96 + o];
        }
    }
    float4 oA, oB;
    oA.x = d * fmaxf(h[0], 0.0f); oA.y = d * fmaxf(h[1], 0.0f);
    oA.z = d * fmaxf(h[2], 0.0f); oA.w = d * fmaxf(h[3], 0.0f);
    oB.x = d * fmaxf(h[4], 0.0f); oB.y = d * fmaxf(h[5], 0.0f);
    oB.z = d * fmaxf(h[6], 0.0f); oB.w = d * fmaxf(h[7], 0.0f);
    float4* O4 = (float4*)out;
    O4[(size_t)i * 8 + q * 2]     = oA;
    O4[(size_t)i * 8 + q * 2 + 1] = oB;
}

// ---- layer-3 agg fused with mm3: h3 = relu( (dinv*Agg(h2d)) @ W3 + b3 )
//      TPN=8 lanes hold the 32-wide a2 row; shfl-broadcast + LDS W3.
__global__ __launch_bounds__(256) void k_aggf32_mm3(const float* __restrict__ T,
        const int* __restrict__ start, const unsigned* __restrict__ poff,
        const int* __restrict__ col, const float* __restrict__ dinv,
        const float* __restrict__ W3, const float* __restrict__ b3,
        float* __restrict__ out, int n) {
    __shared__ float sW[32 * 64];
    __shared__ float sB[64];
    int t = threadIdx.x;
    for (int j = t; j < 2048; j += 256) sW[j] = W3[j];
    if (t < 64) sB[t] = b3[t];
    __syncthreads();
    int idx = blockIdx.x * blockDim.x + t;
    int i = idx / 8, q = idx % 8;
    if (i >= n) return;
    float4 acc = agg_gather<8>((const float4*)T, col, start[i], poff[i], q,
                               (size_t)i * 8 + q);
    float d = dinv[i];
    acc.x *= d; acc.y *= d; acc.z *= d; acc.w *= d;  // a2 fragment
    int lane = t & 63;
    int gbase = lane & ~7;  // 8-lane group base
    float h[8];
    #pragma unroll
    for (int o = 0; o < 8; ++o) h[o] = sB[q * 8 + o];
    #pragma unroll
    for (int j = 0; j < 8; ++j) {
        float ax = __shfl(acc.x, gbase + j);
        float ay = __shfl(acc.y, gbase + j);
        float az = __shfl(acc.z, gbase + j);
        float aw = __shfl(acc.w, gbase + j);
        const float* w0 = &sW[(4 * j) * 64 + q * 8];
        #pragma unroll
        for (int o = 0; o < 8; ++o) {
            h[o] += ax * w0[o] + ay * w0[64 + o] + az * w0[128 + o] + aw * w0[192 + o];
        }
    }
    float4 oA, oB;
    oA.x = fmaxf(h[0], 0.0f); oA.y = fmaxf(h[1], 0.0f);
    oA.z = fmaxf(h[2], 0.0f); oA.w = fmaxf(h[3], 0.0f);
    oB.x = fmaxf(h[4], 0.0f); oB.y = fmaxf(h[5], 0.0f);
    oB.z = fmaxf(h[6], 0.0f); oB.w = fmaxf(h[7], 0.0f);
    float4* O4 = (float4*)out;
    O4[(size_t)i * 16 + q * 2]     = oA;
    O4[(size_t)i * 16 + q * 2 + 1] = oB;
}

// ---- mm1: Pd1 = dinv * (x @ W1), K=128 F=16. LDS-tiled.
__global__ __launch_bounds__(256) void k_mm1(const float4* __restrict__ X4,
        const float4* __restrict__ W4, const float* __restrict__ dinv,
        float* __restrict__ out, int n) {
    __shared__ float4 xs[64 * 32];
    __shared__ float4 ws[512];
    int t = threadIdx.x;
    int nb = blockIdx.x * 64;
    ws[t] = W4[t]; ws[t + 256] = W4[t + 256];
    int lim = min(64, n - nb);
    #pragma unroll
    for (int it = 0; it < 8; ++it) {
        int idx = it * 256 + t;
        if ((idx >> 5) < lim) xs[idx] = X4[(size_t)nb * 32 + idx];
    }
    __syncthreads();
    int lane = t & 63, wv = t >> 6;
    int f = lane & 15, kc = lane >> 4;
    float wcol[32];
    #pragma unroll
    for (int kk = 0; kk < 32; ++kk)
        wcol[kk] = ((const float*)ws)[(kc * 32 + kk) * 16 + f];
    for (int ln = wv * 16; ln < wv * 16 + 16; ++ln) {
        if (ln >= lim) break;
        int i = nb + ln;
        float acc = 0.0f;
        #pragma unroll
        for (int j = 0; j < 8; ++j) {
            float4 hv = xs[ln * 32 + kc * 8 + j];
            acc += hv.x * wcol[4 * j]     + hv.y * wcol[4 * j + 1]
                 + hv.z * wcol[4 * j + 2] + hv.w * wcol[4 * j + 3];
        }
        acc += __shfl_xor(acc, 16);
        acc += __shfl_xor(acc, 32);
        if (kc == 0) out[(size_t)i * 16 + f] = acc * dinv[i];
    }
}

// ---- fused mean-pool + MLP head: 256 threads per graph (4-way row parallel)
__global__ __launch_bounds__(256) void k_poolhead(const float* __restrict__ h3,
        const int* __restrict__ batch, const float* __restrict__ Wl1,
        const float* __restrict__ bl1, const float* __restrict__ Wl2,
        const float* __restrict__ bl2, float* __restrict__ out, int n) {
    int g = blockIdx.x, t = threadIdx.x;
    int f = t & 63, r = t >> 6;
    __shared__ int sb[2];
    __shared__ float part[4][64];
    __shared__ float mean[64], hid[64];
    if (t < 2) {
        int target = g + t;
        int lo = 0, hi = n;
        while (lo < hi) {
            int mid = (lo + hi) >> 1;
            if (batch[mid] < target) lo = mid + 1; else hi = mid;
        }
        sb[t] = lo;
    }
    __syncthreads();
    int s = sb[0], e = sb[1];
    float acc = 0.0f;
    for (int i = s + r; i < e; i += 4) acc += h3[(size_t)i * 64 + f];
    part[r][f] = acc;
    __syncthreads();
    if (t < 64) {
        float c = fmaxf((float)(e - s), 1.0f);
        mean[t] = (part[0][t] + part[1][t] + part[2][t] + part[3][t]) / c;
    }
    __syncthreads();
    if (t < 64) {
        float a = bl1[t];
        #pragma unroll 8
        for (int k = 0; k < 64; ++k) a += mean[k] * Wl1[k * 64 + t];
        hid[t] = fmaxf(a, 0.0f);
    }
    __syncthreads();
    if (t < 2) {
        float o = bl2[t];
        #pragma unroll 8
        for (int k = 0; k < 64; ++k) o += hid[k] * Wl2[k * 2 + t];
        out[g * 2 + t] = o;
    }
}

extern "C" void kernel_launch(void* const* d_in, const int* in_sizes, int n_in,
                              void* d_out, int out_size, void* d_ws, size_t ws_size,
                              hipStream_t stream) {
    const float* x    = (const float*)d_in[0];
    const int*   ei   = (const int*)d_in[1];
    const int*   batch= (const int*)d_in[2];
    const float* W1   = (const float*)d_in[3];
    const float* b1   = (const float*)d_in[4];
    const float* W2   = (const float*)d_in[5];
    const float* b2   = (const float*)d_in[6];
    const float* W3   = (const float*)d_in[7];
    const float* b3   = (const float*)d_in[8];
    const float* Wl1  = (const float*)d_in[9];
    const float* bl1  = (const float*)d_in[10];
    const float* Wl2  = (const float*)d_in[11];
    const float* bl2  = (const float*)d_in[12];
    float* out = (float*)d_out;

    const int n  = in_sizes[2];      // 100000
    const int nE = in_sizes[1] / 2;  // 3200000
    const int* src = ei;
    const int* dst = ei + nE;

    const int NSB   = (n + NPSB - 1) / NPSB;   // 196 super-buckets (512 nodes)
    const int NBLK1 = (nE + EPA1 - 1) / EPA1;  // 196 level-1 blocks
    const int NG    = 1024;
    const int qsz   = (n + 3) / 4;             // src-quartile size

    char* w = (char*)d_ws;
    auto alloc_f = [&](size_t cnt) { float* p = (float*)w; w += cnt * 4; return p; };
    auto alloc_i = [&](size_t cnt) { int*   p = (int*)w;   w += cnt * 4; return p; };

    float*    dinv   = alloc_f(n);
    int*      start  = alloc_i(n);
    unsigned* poff   = (unsigned*)alloc_i(n);
    int*      cnt1   = alloc_i((size_t)NBLK1 * PAD1);
    int*      po1    = alloc_i((size_t)NBLK1 * PAD1);
    int*      totals = alloc_i(256);
    unsigned* ebuf   = (unsigned*)alloc_i(nE);   // 12.8 MB
    int*      col    = alloc_i(nE);              // 12.8 MB
    float* Pd1 = alloc_f((size_t)n * 16);
    float* h1d = alloc_f((size_t)n * 16);
    float* h2d = alloc_f((size_t)n * 32);
    float* h3  = alloc_f((size_t)n * 64);  // own buffer: col is live during fused agg3
    float* pd  = Pd1;  (void)pd;

    const int B = 256;
    auto g = [&](long long t) { return (int)((t + B - 1) / B); };

    // ---- CSR build: two-level radix, zero global atomics
    k_hist1<<<NBLK1, 1024, 0, stream>>>(dst, cnt1, nE, NSB);
    k_scan1<<<NSB, 256, 0, stream>>>(cnt1, po1, totals, NBLK1);
    k_scat1<<<NBLK1, 1024, 0, stream>>>(src, dst, po1, totals, ebuf, nE, NSB);
    k_sort2<<<NSB, 512, 0, stream>>>(ebuf, totals, col, start, dinv, poff, n, qsz, NSB);

    // ---- layer 1: Pd1 = dinv*(x@W1); h1d = dinv*relu(dinv*Agg(Pd1)+b1)
    k_mm1<<<(n + 63) / 64, 256, 0, stream>>>((const float4*)x, (const float4*)W1,
                                             dinv, Pd1, n);
    k_aggf16<<<g((long long)n * 4), B, 0, stream>>>(Pd1, start, poff, col, dinv, b1, h1d, n);

    // ---- layer 2 (agg + mm2 fused): h2d = dinv*relu((dinv*Agg(h1d))@W2+b2)
    k_aggf16_mm2<<<g((long long)n * 4), B, 0, stream>>>(h1d, start, poff, col, dinv,
                                                        W2, b2, h2d, n);

    // ---- layer 3 (agg + mm3 fused): h3 = relu((dinv*Agg(h2d))@W3+b3)
    k_aggf32_mm3<<<g((long long)n * 8), B, 0, stream>>>(h2d, start, poff, col, dinv,
                                                        W3, b3, h3, n);

    // ---- fused mean-pool + head (no atomics; batch is sorted)
    k_poolhead<<<NG, 256, 0, stream>>>(h3, batch, Wl1, bl1, Wl2, bl2, out, n);
}

// Round 15
// 231.162 us; speedup vs baseline: 1.1840x; 1.0308x over previous
//
#include <hip/hip_runtime.h>

// GCN forward: 3x GCNConv (symmetric norm, self-loops) + mean-pool + MLP head.
// R15: R14 + CSR-build occupancy fix: 256-node super-buckets / 8192-edge L1
//      chunks -> 392 blocks (was 196 = <1 block/CU) for hist1/scat1/sort2.
//      aggf32_mm3 at 512 threads (W3 staging amortized 2x).

constexpr int EPA1 = 8192;   // edges per level-1 block
constexpr int NPSB = 256;    // nodes per super-bucket
constexpr int PAD1 = 400;    // [blk][sb] metadata row stride

// ---- level 1 histogram: per-block super-bucket counts
__global__ __launch_bounds__(1024) void k_hist1(const int* __restrict__ dst,
        int* __restrict__ cnt1, int nE, int NSB) {
    __shared__ int hist[512];
    int t = threadIdx.x;
    if (t < 512) hist[t] = 0;
    __syncthreads();
    int base = blockIdx.x * EPA1, end = min(base + EPA1, nE);
    for (int e = base + t; e < end; e += 1024)
        atomicAdd(&hist[dst[e] >> 8], 1);  // LDS
    __syncthreads();
    if (t < NSB) cnt1[blockIdx.x * PAD1 + t] = hist[t];
}

// ---- level 1 scan: per-sb exclusive prefix over blocks; emits totals
__global__ __launch_bounds__(512) void k_scan1(const int* __restrict__ cnt1,
        int* __restrict__ po1, int* __restrict__ totals, int NBLK1) {
    __shared__ int sc[512];
    int sb = blockIdx.x, t = threadIdx.x;
    int v = (t < NBLK1) ? cnt1[t * PAD1 + sb] : 0;
    sc[t] = v;
    __syncthreads();
    for (int off = 1; off < 512; off <<= 1) {
        int u = (t >= off) ? sc[t - off] : 0;
        __syncthreads();
        sc[t] += u;
        __syncthreads();
    }
    if (t < NBLK1) po1[t * PAD1 + sb] = sc[t] - v;
    if (t == 511) totals[sb] = sc[511];
}

// ---- level 1 scatter: edges -> super-bucket-major ebuf (packed lnode|src).
__global__ __launch_bounds__(1024) void k_scat1(const int* __restrict__ src,
        const int* __restrict__ dst, const int* __restrict__ po1,
        const int* __restrict__ totals, unsigned* __restrict__ ebuf,
        int nE, int NSB) {
    __shared__ int sc[512], cur[512];
    int t = threadIdx.x, blk = blockIdx.x;
    if (t < 512) sc[t] = (t < NSB) ? totals[t] : 0;
    __syncthreads();
    for (int off = 1; off < 512; off <<= 1) {
        int u = (t >= off && t < 512) ? sc[t - off] : 0;
        __syncthreads();
        if (t < 512) sc[t] += u;
        __syncthreads();
    }
    if (t < NSB) cur[t] = (sc[t] - totals[t]) + po1[blk * PAD1 + t];
    __syncthreads();
    int base = blk * EPA1, end = min(base + EPA1, nE);
    for (int e = base + t; e < end; e += 1024) {
        int s = src[e], d = dst[e];
        int pos = atomicAdd(&cur[d >> 8], 1);  // LDS
        ebuf[pos] = ((unsigned)(d & 255) << 17) | (unsigned)s;  // ~167B segments
    }
}

// ---- level 2: per-sb contiguous counting sort by (node, src-quartile)
__global__ __launch_bounds__(512) void k_sort2(const unsigned* __restrict__ ebuf,
        const int* __restrict__ totals, int* __restrict__ col,
        int* __restrict__ start, float* __restrict__ dinv,
        unsigned* __restrict__ poff, int n, int qsz, int NSB) {
    __shared__ int sc[512];
    __shared__ int hist4[1024], cur4[1024], excl[256];
    int b = blockIdx.x, t = threadIdx.x;
    sc[t] = (t < NSB) ? totals[t] : 0;
    __syncthreads();
    for (int off = 1; off < 512; off <<= 1) {
        int u = (t >= off) ? sc[t - off] : 0;
        __syncthreads();
        sc[t] += u;
        __syncthreads();
    }
    int eend = sc[b], ebase = eend - totals[b];
    hist4[t] = 0; hist4[t + 512] = 0;
    __syncthreads();
    for (int e = ebase + t; e < eend; e += 512) {
        unsigned u = ebuf[e];  // contiguous stream
        atomicAdd(&hist4[(u >> 17) * 4 + (int)(u & 0x1FFFFu) / qsz], 1);  // LDS
    }
    __syncthreads();
    int c0 = 0, c1 = 0, c2 = 0, c3 = 0, v = 0;
    if (t < 256) {
        c0 = hist4[t * 4];     c1 = hist4[t * 4 + 1];
        c2 = hist4[t * 4 + 2]; c3 = hist4[t * 4 + 3];
        v = c0 + c1 + c2 + c3;
        excl[t] = v;
    }
    __syncthreads();
    for (int off = 1; off < 256; off <<= 1) {
        int u = (t >= off && t < 256) ? excl[t - off] : 0;
        __syncthreads();
        if (t < 256) excl[t] += u;
        __syncthreads();
    }
    if (t < 256) {
        int sbase = ebase + excl[t] - v;
        cur4[t * 4]     = sbase;
        cur4[t * 4 + 1] = sbase + c0;
        cur4[t * 4 + 2] = sbase + c0 + c1;
        cur4[t * 4 + 3] = sbase + c0 + c1 + c2;
        int node = (b << 8) + t;
        if (node < n) {
            start[node] = sbase;
            dinv[node] = rsqrtf((float)(v + 1));
            poff[node] = (unsigned)c0 | ((unsigned)c1 << 8) |
                         ((unsigned)c2 << 16) | ((unsigned)c3 << 24);
        }
    }
    __syncthreads();
    for (int e = ebase + t; e < eend; e += 512) {
        unsigned u = ebuf[e];  // L2-hot (read in pass 1)
        int s = (int)(u & 0x1FFFFu);
        int pos = atomicAdd(&cur4[(u >> 17) * 4 + s / qsz], 1);  // LDS
        col[pos] = s;  // ~32KB window
    }
}

// ---- shared gather body: quartile loop, register accumulator (R11 shape)
template <int TPN>
__device__ __forceinline__ float4 agg_gather(const float4* __restrict__ T4,
        const int* __restrict__ col, int base, unsigned pk, int q, size_t selfIdx) {
    float4 acc = T4[selfIdx];  // self term
    #pragma unroll
    for (int p = 0; p < 4; ++p) {
        int len = (int)((pk >> (8 * p)) & 255u);
        int k = 0;
        for (; k + 4 <= len; k += 4) {
            int s0 = col[base + k],     s1 = col[base + k + 1];
            int s2 = col[base + k + 2], s3 = col[base + k + 3];
            float4 v0 = T4[(size_t)s0 * TPN + q];
            float4 v1 = T4[(size_t)s1 * TPN + q];
            float4 v2 = T4[(size_t)s2 * TPN + q];
            float4 v3 = T4[(size_t)s3 * TPN + q];
            acc.x += v0.x + v1.x + v2.x + v3.x;
            acc.y += v0.y + v1.y + v2.y + v3.y;
            acc.z += v0.z + v1.z + v2.z + v3.z;
            acc.w += v0.w + v1.w + v2.w + v3.w;
        }
        for (; k < len; ++k) {
            float4 v = T4[(size_t)col[base + k] * TPN + q];
            acc.x += v.x; acc.y += v.y; acc.z += v.z; acc.w += v.w;
        }
        base += len;
    }
    return acc;
}

// ---- layer-1 agg (F=16, EPI: bias+relu+prescale)
__global__ void k_aggf16(const float* __restrict__ T, const int* __restrict__ start,
        const unsigned* __restrict__ poff, const int* __restrict__ col,
        const float* __restrict__ dinv, const float* __restrict__ bias,
        float* __restrict__ out, int n) {
    int idx = blockIdx.x * blockDim.x + threadIdx.x;
    int i = idx / 4, q = idx % 4;
    if (i >= n) return;
    float4 acc = agg_gather<4>((const float4*)T, col, start[i], poff[i], q,
                               (size_t)i * 4 + q);
    float d = dinv[i];
    float4 b = ((const float4*)bias)[q];
    float4 o;
    o.x = d * fmaxf(d * acc.x + b.x, 0.0f);
    o.y = d * fmaxf(d * acc.y + b.y, 0.0f);
    o.z = d * fmaxf(d * acc.z + b.z, 0.0f);
    o.w = d * fmaxf(d * acc.w + b.w, 0.0f);
    ((float4*)out)[(size_t)i * 4 + q] = o;
}

// ---- layer-2 agg fused with mm2: h2d = dinv*relu( (dinv*Agg(h1d)) @ W2 + b2 )
__global__ __launch_bounds__(256) void k_aggf16_mm2(const float* __restrict__ T,
        const int* __restrict__ start, const unsigned* __restrict__ poff,
        const int* __restrict__ col, const float* __restrict__ dinv,
        const float* __restrict__ W2, const float* __restrict__ b2,
        float* __restrict__ out, int n) {
    __shared__ float sW[16 * 32];
    __shared__ float sB[32];
    int t = threadIdx.x;
    for (int j = t; j < 512; j += 256) sW[j] = W2[j];
    if (t < 32) sB[t] = b2[t];
    __syncthreads();
    int idx = blockIdx.x * blockDim.x + t;
    int i = idx / 4, q = idx % 4;
    if (i >= n) return;
    float4 acc = agg_gather<4>((const float4*)T, col, start[i], poff[i], q,
                               (size_t)i * 4 + q);
    float d = dinv[i];
    acc.x *= d; acc.y *= d; acc.z *= d; acc.w *= d;  // a1 fragment
    int lane = t & 63;
    int gbase = lane & ~3;  // 4-lane group base
    float h[8];
    #pragma unroll
    for (int o = 0; o < 8; ++o) h[o] = sB[q * 8 + o];
    #pragma unroll
    for (int j = 0; j < 4; ++j) {
        float ax = __shfl(acc.x, gbase + j);
        float ay = __shfl(acc.y, gbase + j);
        float az = __shfl(acc.z, gbase + j);
        float aw = __shfl(acc.w, gbase + j);
        const float* w0 = &sW[(4 * j) * 32 + q * 8];
        #pragma unroll
        for (int o = 0; o < 8; ++o) {
            h[o] += ax * w0[o] + ay * w0[32 + o] + az * w0[64 + o] + aw * w0[96 + o];
        }
    }
    float4 oA, oB;
    oA.x = d * fmaxf(h[0], 0.0f); oA.y = d * fmaxf(h[1], 0.0f);
    oA.z = d * fmaxf(h[2], 0.0f); oA.w = d * fmaxf(h[3], 0.0f);
    oB.x = d * fmaxf(h[4], 0.0f); oB.y = d * fmaxf(h[5], 0.0f);
    oB.z = d * fmaxf(h[6], 0.0f); oB.w = d * fmaxf(h[7], 0.0f);
    float4* O4 = (float4*)out;
    O4[(size_t)i * 8 + q * 2]     = oA;
    O4[(size_t)i * 8 + q * 2 + 1] = oB;
}

// ---- layer-3 agg fused with mm3: h3 = relu( (dinv*Agg(h2d)) @ W3 + b3 )
__global__ __launch_bounds__(512) void k_aggf32_mm3(const float* __restrict__ T,
        const int* __restrict__ start, const unsigned* __restrict__ poff,
        const int* __restrict__ col, const float* __restrict__ dinv,
        const float* __restrict__ W3, const float* __restrict__ b3,
        float* __restrict__ out, int n) {
    __shared__ float sW[32 * 64];
    __shared__ float sB[64];
    int t = threadIdx.x;
    for (int j = t; j < 2048; j += 512) sW[j] = W3[j];
    if (t < 64) sB[t] = b3[t];
    __syncthreads();
    int idx = blockIdx.x * blockDim.x + t;
    int i = idx / 8, q = idx % 8;
    if (i >= n) return;
    float4 acc = agg_gather<8>((const float4*)T, col, start[i], poff[i], q,
                               (size_t)i * 8 + q);
    float d = dinv[i];
    acc.x *= d; acc.y *= d; acc.z *= d; acc.w *= d;  // a2 fragment
    int lane = t & 63;
    int gbase = lane & ~7;  // 8-lane group base
    float h[8];
    #pragma unroll
    for (int o = 0; o < 8; ++o) h[o] = sB[q * 8 + o];
    #pragma unroll
    for (int j = 0; j < 8; ++j) {
        float ax = __shfl(acc.x, gbase + j);
        float ay = __shfl(acc.y, gbase + j);
        float az = __shfl(acc.z, gbase + j);
        float aw = __shfl(acc.w, gbase + j);
        const float* w0 = &sW[(4 * j) * 64 + q * 8];
        #pragma unroll
        for (int o = 0; o < 8; ++o) {
            h[o] += ax * w0[o] + ay * w0[64 + o] + az * w0[128 + o] + aw * w0[192 + o];
        }
    }
    float4 oA, oB;
    oA.x = fmaxf(h[0], 0.0f); oA.y = fmaxf(h[1], 0.0f);
    oA.z = fmaxf(h[2], 0.0f); oA.w = fmaxf(h[3], 0.0f);
    oB.x = fmaxf(h[4], 0.0f); oB.y = fmaxf(h[5], 0.0f);
    oB.z = fmaxf(h[6], 0.0f); oB.w = fmaxf(h[7], 0.0f);
    float4* O4 = (float4*)out;
    O4[(size_t)i * 16 + q * 2]     = oA;
    O4[(size_t)i * 16 + q * 2 + 1] = oB;
}

// ---- mm1: Pd1 = dinv * (x @ W1), K=128 F=16. LDS-tiled.
__global__ __launch_bounds__(256) void k_mm1(const float4* __restrict__ X4,
        const float4* __restrict__ W4, const float* __restrict__ dinv,
        float* __restrict__ out, int n) {
    __shared__ float4 xs[64 * 32];
    __shared__ float4 ws[512];
    int t = threadIdx.x;
    int nb = blockIdx.x * 64;
    ws[t] = W4[t]; ws[t + 256] = W4[t + 256];
    int lim = min(64, n - nb);
    #pragma unroll
    for (int it = 0; it < 8; ++it) {
        int idx = it * 256 + t;
        if ((idx >> 5) < lim) xs[idx] = X4[(size_t)nb * 32 + idx];
    }
    __syncthreads();
    int lane = t & 63, wv = t >> 6;
    int f = lane & 15, kc = lane >> 4;
    float wcol[32];
    #pragma unroll
    for (int kk = 0; kk < 32; ++kk)
        wcol[kk] = ((const float*)ws)[(kc * 32 + kk) * 16 + f];
    for (int ln = wv * 16; ln < wv * 16 + 16; ++ln) {
        if (ln >= lim) break;
        int i = nb + ln;
        float acc = 0.0f;
        #pragma unroll
        for (int j = 0; j < 8; ++j) {
            float4 hv = xs[ln * 32 + kc * 8 + j];
            acc += hv.x * wcol[4 * j]     + hv.y * wcol[4 * j + 1]
                 + hv.z * wcol[4 * j + 2] + hv.w * wcol[4 * j + 3];
        }
        acc += __shfl_xor(acc, 16);
        acc += __shfl_xor(acc, 32);
        if (kc == 0) out[(size_t)i * 16 + f] = acc * dinv[i];
    }
}

// ---- fused mean-pool + MLP head: 256 threads per graph (4-way row parallel)
__global__ __launch_bounds__(256) void k_poolhead(const float* __restrict__ h3,
        const int* __restrict__ batch, const float* __restrict__ Wl1,
        const float* __restrict__ bl1, const float* __restrict__ Wl2,
        const float* __restrict__ bl2, float* __restrict__ out, int n) {
    int g = blockIdx.x, t = threadIdx.x;
    int f = t & 63, r = t >> 6;
    __shared__ int sb[2];
    __shared__ float part[4][64];
    __shared__ float mean[64], hid[64];
    if (t < 2) {
        int target = g + t;
        int lo = 0, hi = n;
        while (lo < hi) {
            int mid = (lo + hi) >> 1;
            if (batch[mid] < target) lo = mid + 1; else hi = mid;
        }
        sb[t] = lo;
    }
    __syncthreads();
    int s = sb[0], e = sb[1];
    float acc = 0.0f;
    for (int i = s + r; i < e; i += 4) acc += h3[(size_t)i * 64 + f];
    part[r][f] = acc;
    __syncthreads();
    if (t < 64) {
        float c = fmaxf((float)(e - s), 1.0f);
        mean[t] = (part[0][t] + part[1][t] + part[2][t] + part[3][t]) / c;
    }
    __syncthreads();
    if (t < 64) {
        float a = bl1[t];
        #pragma unroll 8
        for (int k = 0; k < 64; ++k) a += mean[k] * Wl1[k * 64 + t];
        hid[t] = fmaxf(a, 0.0f);
    }
    __syncthreads();
    if (t < 2) {
        float o = bl2[t];
        #pragma unroll 8
        for (int k = 0; k < 64; ++k) o += hid[k] * Wl2[k * 2 + t];
        out[g * 2 + t] = o;
    }
}

extern "C" void kernel_launch(void* const* d_in, const int* in_sizes, int n_in,
                              void* d_out, int out_size, void* d_ws, size_t ws_size,
                              hipStream_t stream) {
    const float* x    = (const float*)d_in[0];
    const int*   ei   = (const int*)d_in[1];
    const int*   batch= (const int*)d_in[2];
    const float* W1   = (const float*)d_in[3];
    const float* b1   = (const float*)d_in[4];
    const float* W2   = (const float*)d_in[5];
    const float* b2   = (const float*)d_in[6];
    const float* W3   = (const float*)d_in[7];
    const float* b3   = (const float*)d_in[8];
    const float* Wl1  = (const float*)d_in[9];
    const float* bl1  = (const float*)d_in[10];
    const float* Wl2  = (const float*)d_in[11];
    const float* bl2  = (const float*)d_in[12];
    float* out = (float*)d_out;

    const int n  = in_sizes[2];      // 100000
    const int nE = in_sizes[1] / 2;  // 3200000
    const int* src = ei;
    const int* dst = ei + nE;

    const int NSB   = (n + NPSB - 1) / NPSB;   // 391 super-buckets (256 nodes)
    const int NBLK1 = (nE + EPA1 - 1) / EPA1;  // 391 level-1 blocks
    const int NG    = 1024;
    const int qsz   = (n + 3) / 4;             // src-quartile size

    char* w = (char*)d_ws;
    auto alloc_f = [&](size_t cnt) { float* p = (float*)w; w += cnt * 4; return p; };
    auto alloc_i = [&](size_t cnt) { int*   p = (int*)w;   w += cnt * 4; return p; };

    float*    dinv   = alloc_f(n);
    int*      start  = alloc_i(n);
    unsigned* poff   = (unsigned*)alloc_i(n);
    int*      cnt1   = alloc_i((size_t)NBLK1 * PAD1);
    int*      po1    = alloc_i((size_t)NBLK1 * PAD1);
    int*      totals = alloc_i(512);
    unsigned* ebuf   = (unsigned*)alloc_i(nE);   // 12.8 MB
    int*      col    = alloc_i(nE);              // 12.8 MB
    float* Pd1 = alloc_f((size_t)n * 16);
    float* h1d = alloc_f((size_t)n * 16);
    float* h2d = alloc_f((size_t)n * 32);
    float* h3  = alloc_f((size_t)n * 64);  // own buffer: col live during fused agg3

    const int B = 256;
    auto g = [&](long long t) { return (int)((t + B - 1) / B); };

    // ---- CSR build: two-level radix, zero global atomics
    k_hist1<<<NBLK1, 1024, 0, stream>>>(dst, cnt1, nE, NSB);
    k_scan1<<<NSB, 512, 0, stream>>>(cnt1, po1, totals, NBLK1);
    k_scat1<<<NBLK1, 1024, 0, stream>>>(src, dst, po1, totals, ebuf, nE, NSB);
    k_sort2<<<NSB, 512, 0, stream>>>(ebuf, totals, col, start, dinv, poff, n, qsz, NSB);

    // ---- layer 1: Pd1 = dinv*(x@W1); h1d = dinv*relu(dinv*Agg(Pd1)+b1)
    k_mm1<<<(n + 63) / 64, 256, 0, stream>>>((const float4*)x, (const float4*)W1,
                                             dinv, Pd1, n);
    k_aggf16<<<g((long long)n * 4), B, 0, stream>>>(Pd1, start, poff, col, dinv, b1, h1d, n);

    // ---- layer 2 (agg + mm2 fused): h2d = dinv*relu((dinv*Agg(h1d))@W2+b2)
    k_aggf16_mm2<<<g((long long)n * 4), B, 0, stream>>>(h1d, start, poff, col, dinv,
                                                        W2, b2, h2d, n);

    // ---- layer 3 (agg + mm3 fused): h3 = relu((dinv*Agg(h2d))@W3+b3)
    k_aggf32_mm3<<<(int)(((long long)n * 8 + 511) / 512), 512, 0, stream>>>(
        h2d, start, poff, col, dinv, W3, b3, h3, n);

    // ---- fused mean-pool + head (no atomics; batch is sorted)
    k_poolhead<<<NG, 256, 0, stream>>>(h3, batch, Wl1, bl1, Wl2, bl2, out, n);
}

// Round 16
// 229.774 us; speedup vs baseline: 1.1911x; 1.0060x over previous
//
#include <hip/hip_runtime.h>
#include <hip/hip_fp16.h>

// GCN forward: 3x GCNConv (symmetric norm, self-loops) + mean-pool + MLP head.
// R16: fp16 storage for gathered intermediates (halves the per-XCD L2 footprint
//      -> halves the agg fetch floor; f32 math throughout) + unroll-8 inside
//      the quartile phases (2 outstanding L2 misses/thread instead of 1).

constexpr int EPA1 = 8192;   // edges per level-1 block
constexpr int NPSB = 256;    // nodes per super-bucket
constexpr int PAD1 = 400;    // [blk][sb] metadata row stride

// ---- fp16 pack/unpack helpers (4 halves <-> uint2)
__device__ __forceinline__ float4 h4f(uint2 u) {
    __half2 a = *reinterpret_cast<__half2*>(&u.x);
    __half2 b = *reinterpret_cast<__half2*>(&u.y);
    float2 fa = __half22float2(a), fb = __half22float2(b);
    return make_float4(fa.x, fa.y, fb.x, fb.y);
}
__device__ __forceinline__ uint2 f4h(float x, float y, float z, float w) {
    __half2 a = __floats2half2_rn(x, y);
    __half2 b = __floats2half2_rn(z, w);
    uint2 u;
    u.x = *reinterpret_cast<unsigned*>(&a);
    u.y = *reinterpret_cast<unsigned*>(&b);
    return u;
}
__device__ __forceinline__ void acc4(float4& a, uint2 u) {
    float4 v = h4f(u);
    a.x += v.x; a.y += v.y; a.z += v.z; a.w += v.w;
}

// ---- level 1 histogram: per-block super-bucket counts
__global__ __launch_bounds__(1024) void k_hist1(const int* __restrict__ dst,
        int* __restrict__ cnt1, int nE, int NSB) {
    __shared__ int hist[512];
    int t = threadIdx.x;
    if (t < 512) hist[t] = 0;
    __syncthreads();
    int base = blockIdx.x * EPA1, end = min(base + EPA1, nE);
    for (int e = base + t; e < end; e += 1024)
        atomicAdd(&hist[dst[e] >> 8], 1);  // LDS
    __syncthreads();
    if (t < NSB) cnt1[blockIdx.x * PAD1 + t] = hist[t];
}

// ---- level 1 scan: per-sb exclusive prefix over blocks; emits totals
__global__ __launch_bounds__(512) void k_scan1(const int* __restrict__ cnt1,
        int* __restrict__ po1, int* __restrict__ totals, int NBLK1) {
    __shared__ int sc[512];
    int sb = blockIdx.x, t = threadIdx.x;
    int v = (t < NBLK1) ? cnt1[t * PAD1 + sb] : 0;
    sc[t] = v;
    __syncthreads();
    for (int off = 1; off < 512; off <<= 1) {
        int u = (t >= off) ? sc[t - off] : 0;
        __syncthreads();
        sc[t] += u;
        __syncthreads();
    }
    if (t < NBLK1) po1[t * PAD1 + sb] = sc[t] - v;
    if (t == 511) totals[sb] = sc[511];
}

// ---- level 1 scatter: edges -> super-bucket-major ebuf (packed lnode|src).
__global__ __launch_bounds__(1024) void k_scat1(const int* __restrict__ src,
        const int* __restrict__ dst, const int* __restrict__ po1,
        const int* __restrict__ totals, unsigned* __restrict__ ebuf,
        int nE, int NSB) {
    __shared__ int sc[512], cur[512];
    int t = threadIdx.x, blk = blockIdx.x;
    if (t < 512) sc[t] = (t < NSB) ? totals[t] : 0;
    __syncthreads();
    for (int off = 1; off < 512; off <<= 1) {
        int u = (t >= off && t < 512) ? sc[t - off] : 0;
        __syncthreads();
        if (t < 512) sc[t] += u;
        __syncthreads();
    }
    if (t < NSB) cur[t] = (sc[t] - totals[t]) + po1[blk * PAD1 + t];
    __syncthreads();
    int base = blk * EPA1, end = min(base + EPA1, nE);
    for (int e = base + t; e < end; e += 1024) {
        int s = src[e], d = dst[e];
        int pos = atomicAdd(&cur[d >> 8], 1);  // LDS
        ebuf[pos] = ((unsigned)(d & 255) << 17) | (unsigned)s;
    }
}

// ---- level 2: per-sb contiguous counting sort by (node, src-quartile)
__global__ __launch_bounds__(512) void k_sort2(const unsigned* __restrict__ ebuf,
        const int* __restrict__ totals, int* __restrict__ col,
        int* __restrict__ start, float* __restrict__ dinv,
        unsigned* __restrict__ poff, int n, int qsz, int NSB) {
    __shared__ int sc[512];
    __shared__ int hist4[1024], cur4[1024], excl[256];
    int b = blockIdx.x, t = threadIdx.x;
    sc[t] = (t < NSB) ? totals[t] : 0;
    __syncthreads();
    for (int off = 1; off < 512; off <<= 1) {
        int u = (t >= off) ? sc[t - off] : 0;
        __syncthreads();
        sc[t] += u;
        __syncthreads();
    }
    int eend = sc[b], ebase = eend - totals[b];
    hist4[t] = 0; hist4[t + 512] = 0;
    __syncthreads();
    for (int e = ebase + t; e < eend; e += 512) {
        unsigned u = ebuf[e];
        atomicAdd(&hist4[(u >> 17) * 4 + (int)(u & 0x1FFFFu) / qsz], 1);  // LDS
    }
    __syncthreads();
    int c0 = 0, c1 = 0, c2 = 0, c3 = 0, v = 0;
    if (t < 256) {
        c0 = hist4[t * 4];     c1 = hist4[t * 4 + 1];
        c2 = hist4[t * 4 + 2]; c3 = hist4[t * 4 + 3];
        v = c0 + c1 + c2 + c3;
        excl[t] = v;
    }
    __syncthreads();
    for (int off = 1; off < 256; off <<= 1) {
        int u = (t >= off && t < 256) ? excl[t - off] : 0;
        __syncthreads();
        if (t < 256) excl[t] += u;
        __syncthreads();
    }
    if (t < 256) {
        int sbase = ebase + excl[t] - v;
        cur4[t * 4]     = sbase;
        cur4[t * 4 + 1] = sbase + c0;
        cur4[t * 4 + 2] = sbase + c0 + c1;
        cur4[t * 4 + 3] = sbase + c0 + c1 + c2;
        int node = (b << 8) + t;
        if (node < n) {
            start[node] = sbase;
            dinv[node] = rsqrtf((float)(v + 1));
            poff[node] = (unsigned)c0 | ((unsigned)c1 << 8) |
                         ((unsigned)c2 << 16) | ((unsigned)c3 << 24);
        }
    }
    __syncthreads();
    for (int e = ebase + t; e < eend; e += 512) {
        unsigned u = ebuf[e];
        int s = (int)(u & 0x1FFFFu);
        int pos = atomicAdd(&cur4[(u >> 17) * 4 + s / qsz], 1);  // LDS
        col[pos] = s;
    }
}

// ---- fp16 gather body: quartile phases preserved (inter-thread L2 alignment),
//      unroll-8 within each phase. RPR = uint2 groups (4 halves) per row.
template <int RPR>
__device__ __forceinline__ float4 agg_gather_h(const uint2* __restrict__ T2,
        const int* __restrict__ col, int base, unsigned pk, int q, size_t selfIdx) {
    float4 acc = h4f(T2[selfIdx]);  // self term
    #pragma unroll
    for (int p = 0; p < 4; ++p) {
        int len = (int)((pk >> (8 * p)) & 255u);
        int k = 0;
        for (; k + 8 <= len; k += 8) {
            uint2 u0 = T2[(size_t)col[base + k]     * RPR + q];
            uint2 u1 = T2[(size_t)col[base + k + 1] * RPR + q];
            uint2 u2 = T2[(size_t)col[base + k + 2] * RPR + q];
            uint2 u3 = T2[(size_t)col[base + k + 3] * RPR + q];
            uint2 u4 = T2[(size_t)col[base + k + 4] * RPR + q];
            uint2 u5 = T2[(size_t)col[base + k + 5] * RPR + q];
            uint2 u6 = T2[(size_t)col[base + k + 6] * RPR + q];
            uint2 u7 = T2[(size_t)col[base + k + 7] * RPR + q];
            acc4(acc, u0); acc4(acc, u1); acc4(acc, u2); acc4(acc, u3);
            acc4(acc, u4); acc4(acc, u5); acc4(acc, u6); acc4(acc, u7);
        }
        for (; k < len; ++k)
            acc4(acc, T2[(size_t)col[base + k] * RPR + q]);
        base += len;
    }
    return acc;
}

// ---- layer-1 agg (F=16 fp16 in/out): h1d = dinv*relu(dinv*Agg(Pd1)+b1)
__global__ void k_aggf16(const uint2* __restrict__ T2, const int* __restrict__ start,
        const unsigned* __restrict__ poff, const int* __restrict__ col,
        const float* __restrict__ dinv, const float* __restrict__ bias,
        uint2* __restrict__ out, int n) {
    int idx = blockIdx.x * blockDim.x + threadIdx.x;
    int i = idx / 4, q = idx % 4;
    if (i >= n) return;
    float4 acc = agg_gather_h<4>(T2, col, start[i], poff[i], q, (size_t)i * 4 + q);
    float d = dinv[i];
    float4 b = ((const float4*)bias)[q];
    out[(size_t)i * 4 + q] = f4h(
        d * fmaxf(d * acc.x + b.x, 0.0f),
        d * fmaxf(d * acc.y + b.y, 0.0f),
        d * fmaxf(d * acc.z + b.z, 0.0f),
        d * fmaxf(d * acc.w + b.w, 0.0f));
}

// ---- layer-2 agg fused with mm2: h2d = dinv*relu( (dinv*Agg(h1d)) @ W2 + b2 )
__global__ __launch_bounds__(256) void k_aggf16_mm2(const uint2* __restrict__ T2,
        const int* __restrict__ start, const unsigned* __restrict__ poff,
        const int* __restrict__ col, const float* __restrict__ dinv,
        const float* __restrict__ W2, const float* __restrict__ b2,
        uint2* __restrict__ out, int n) {
    __shared__ float sW[16 * 32];
    __shared__ float sB[32];
    int t = threadIdx.x;
    for (int j = t; j < 512; j += 256) sW[j] = W2[j];
    if (t < 32) sB[t] = b2[t];
    __syncthreads();
    int idx = blockIdx.x * blockDim.x + t;
    int i = idx / 4, q = idx % 4;
    if (i >= n) return;
    float4 acc = agg_gather_h<4>(T2, col, start[i], poff[i], q, (size_t)i * 4 + q);
    float d = dinv[i];
    acc.x *= d; acc.y *= d; acc.z *= d; acc.w *= d;  // a1 fragment
    int lane = t & 63;
    int gbase = lane & ~3;
    float h[8];
    #pragma unroll
    for (int o = 0; o < 8; ++o) h[o] = sB[q * 8 + o];
    #pragma unroll
    for (int j = 0; j < 4; ++j) {
        float ax = __shfl(acc.x, gbase + j);
        float ay = __shfl(acc.y, gbase + j);
        float az = __shfl(acc.z, gbase + j);
        float aw = __shfl(acc.w, gbase + j);
        const float* w0 = &sW[(4 * j) * 32 + q * 8];
        #pragma unroll
        for (int o = 0; o < 8; ++o) {
            h[o] += ax * w0[o] + ay * w0[32 + o] + az * w0[64 + o] + aw * w0[96 + o];
        }
    }
    out[(size_t)i * 8 + q * 2] = f4h(
        d * fmaxf(h[0], 0.0f), d * fmaxf(h[1], 0.0f),
        d * fmaxf(h[2], 0.0f), d * fmaxf(h[3], 0.0f));
    out[(size_t)i * 8 + q * 2 + 1] = f4h(
        d * fmaxf(h[4], 0.0f), d * fmaxf(h[5], 0.0f),
        d * fmaxf(h[6], 0.0f), d * fmaxf(h[7], 0.0f));
}

// ---- layer-3 agg fused with mm3: h3 = relu( (dinv*Agg(h2d)) @ W3 + b3 )
__global__ __launch_bounds__(512) void k_aggf32_mm3(const uint2* __restrict__ T2,
        const int* __restrict__ start, const unsigned* __restrict__ poff,
        const int* __restrict__ col, const float* __restrict__ dinv,
        const float* __restrict__ W3, const float* __restrict__ b3,
        float* __restrict__ out, int n) {
    __shared__ float sW[32 * 64];
    __shared__ float sB[64];
    int t = threadIdx.x;
    for (int j = t; j < 2048; j += 512) sW[j] = W3[j];
    if (t < 64) sB[t] = b3[t];
    __syncthreads();
    int idx = blockIdx.x * blockDim.x + t;
    int i = idx / 8, q = idx % 8;
    if (i >= n) return;
    float4 acc = agg_gather_h<8>(T2, col, start[i], poff[i], q, (size_t)i * 8 + q);
    float d = dinv[i];
    acc.x *= d; acc.y *= d; acc.z *= d; acc.w *= d;  // a2 fragment
    int lane = t & 63;
    int gbase = lane & ~7;
    float h[8];
    #pragma unroll
    for (int o = 0; o < 8; ++o) h[o] = sB[q * 8 + o];
    #pragma unroll
    for (int j = 0; j < 8; ++j) {
        float ax = __shfl(acc.x, gbase + j);
        float ay = __shfl(acc.y, gbase + j);
        float az = __shfl(acc.z, gbase + j);
        float aw = __shfl(acc.w, gbase + j);
        const float* w0 = &sW[(4 * j) * 64 + q * 8];
        #pragma unroll
        for (int o = 0; o < 8; ++o) {
            h[o] += ax * w0[o] + ay * w0[64 + o] + az * w0[128 + o] + aw * w0[192 + o];
        }
    }
    float4 oA, oB;
    oA.x = fmaxf(h[0], 0.0f); oA.y = fmaxf(h[1], 0.0f);
    oA.z = fmaxf(h[2], 0.0f); oA.w = fmaxf(h[3], 0.0f);
    oB.x = fmaxf(h[4], 0.0f); oB.y = fmaxf(h[5], 0.0f);
    oB.z = fmaxf(h[6], 0.0f); oB.w = fmaxf(h[7], 0.0f);
    float4* O4 = (float4*)out;
    O4[(size_t)i * 16 + q * 2]     = oA;
    O4[(size_t)i * 16 + q * 2 + 1] = oB;
}

// ---- mm1: Pd1 (fp16) = dinv * (x @ W1), K=128 F=16. LDS-tiled.
__global__ __launch_bounds__(256) void k_mm1(const float4* __restrict__ X4,
        const float4* __restrict__ W4, const float* __restrict__ dinv,
        __half* __restrict__ out, int n) {
    __shared__ float4 xs[64 * 32];
    __shared__ float4 ws[512];
    int t = threadIdx.x;
    int nb = blockIdx.x * 64;
    ws[t] = W4[t]; ws[t + 256] = W4[t + 256];
    int lim = min(64, n - nb);
    #pragma unroll
    for (int it = 0; it < 8; ++it) {
        int idx = it * 256 + t;
        if ((idx >> 5) < lim) xs[idx] = X4[(size_t)nb * 32 + idx];
    }
    __syncthreads();
    int lane = t & 63, wv = t >> 6;
    int f = lane & 15, kc = lane >> 4;
    float wcol[32];
    #pragma unroll
    for (int kk = 0; kk < 32; ++kk)
        wcol[kk] = ((const float*)ws)[(kc * 32 + kk) * 16 + f];
    for (int ln = wv * 16; ln < wv * 16 + 16; ++ln) {
        if (ln >= lim) break;
        int i = nb + ln;
        float acc = 0.0f;
        #pragma unroll
        for (int j = 0; j < 8; ++j) {
            float4 hv = xs[ln * 32 + kc * 8 + j];
            acc += hv.x * wcol[4 * j]     + hv.y * wcol[4 * j + 1]
                 + hv.z * wcol[4 * j + 2] + hv.w * wcol[4 * j + 3];
        }
        acc += __shfl_xor(acc, 16);
        acc += __shfl_xor(acc, 32);
        if (kc == 0) out[(size_t)i * 16 + f] = __float2half_rn(acc * dinv[i]);
    }
}

// ---- fused mean-pool + MLP head: 256 threads per graph (4-way row parallel)
__global__ __launch_bounds__(256) void k_poolhead(const float* __restrict__ h3,
        const int* __restrict__ batch, const float* __restrict__ Wl1,
        const float* __restrict__ bl1, const float* __restrict__ Wl2,
        const float* __restrict__ bl2, float* __restrict__ out, int n) {
    int g = blockIdx.x, t = threadIdx.x;
    int f = t & 63, r = t >> 6;
    __shared__ int sb[2];
    __shared__ float part[4][64];
    __shared__ float mean[64], hid[64];
    if (t < 2) {
        int target = g + t;
        int lo = 0, hi = n;
        while (lo < hi) {
            int mid = (lo + hi) >> 1;
            if (batch[mid] < target) lo = mid + 1; else hi = mid;
        }
        sb[t] = lo;
    }
    __syncthreads();
    int s = sb[0], e = sb[1];
    float acc = 0.0f;
    for (int i = s + r; i < e; i += 4) acc += h3[(size_t)i * 64 + f];
    part[r][f] = acc;
    __syncthreads();
    if (t < 64) {
        float c = fmaxf((float)(e - s), 1.0f);
        mean[t] = (part[0][t] + part[1][t] + part[2][t] + part[3][t]) / c;
    }
    __syncthreads();
    if (t < 64) {
        float a = bl1[t];
        #pragma unroll 8
        for (int k = 0; k < 64; ++k) a += mean[k] * Wl1[k * 64 + t];
        hid[t] = fmaxf(a, 0.0f);
    }
    __syncthreads();
    if (t < 2) {
        float o = bl2[t];
        #pragma unroll 8
        for (int k = 0; k < 64; ++k) o += hid[k] * Wl2[k * 2 + t];
        out[g * 2 + t] = o;
    }
}

extern "C" void kernel_launch(void* const* d_in, const int* in_sizes, int n_in,
                              void* d_out, int out_size, void* d_ws, size_t ws_size,
                              hipStream_t stream) {
    const float* x    = (const float*)d_in[0];
    const int*   ei   = (const int*)d_in[1];
    const int*   batch= (const int*)d_in[2];
    const float* W1   = (const float*)d_in[3];
    const float* b1   = (const float*)d_in[4];
    const float* W2   = (const float*)d_in[5];
    const float* b2   = (const float*)d_in[6];
    const float* W3   = (const float*)d_in[7];
    const float* b3   = (const float*)d_in[8];
    const float* Wl1  = (const float*)d_in[9];
    const float* bl1  = (const float*)d_in[10];
    const float* Wl2  = (const float*)d_in[11];
    const float* bl2  = (const float*)d_in[12];
    float* out = (float*)d_out;

    const int n  = in_sizes[2];      // 100000
    const int nE = in_sizes[1] / 2;  // 3200000
    const int* src = ei;
    const int* dst = ei + nE;

    const int NSB   = (n + NPSB - 1) / NPSB;   // 391 super-buckets (256 nodes)
    const int NBLK1 = (nE + EPA1 - 1) / EPA1;  // 391 level-1 blocks
    const int NG    = 1024;
    const int qsz   = (n + 3) / 4;             // src-quartile size

    char* w = (char*)d_ws;
    auto alloc_f = [&](size_t cnt) { float* p = (float*)w; w += cnt * 4; return p; };
    auto alloc_i = [&](size_t cnt) { int*   p = (int*)w;   w += cnt * 4; return p; };
    auto alloc_h = [&](size_t cnt) { __half* p = (__half*)w; w += cnt * 2; return p; };

    float*    dinv   = alloc_f(n);
    int*      start  = alloc_i(n);
    unsigned* poff   = (unsigned*)alloc_i(n);
    int*      cnt1   = alloc_i((size_t)NBLK1 * PAD1);
    int*      po1    = alloc_i((size_t)NBLK1 * PAD1);
    int*      totals = alloc_i(512);
    unsigned* ebuf   = (unsigned*)alloc_i(nE);   // 12.8 MB
    int*      col    = alloc_i(nE);              // 12.8 MB
    __half* Pd1 = alloc_h((size_t)n * 16);  // 3.2 MB fp16
    __half* h1d = alloc_h((size_t)n * 16);  // 3.2 MB fp16
    __half* h2d = alloc_h((size_t)n * 32);  // 6.4 MB fp16
    float*  h3  = alloc_f((size_t)n * 64);  // f32 (feeds poolhead)

    const int B = 256;
    auto g = [&](long long t) { return (int)((t + B - 1) / B); };

    // ---- CSR build: two-level radix, zero global atomics
    k_hist1<<<NBLK1, 1024, 0, stream>>>(dst, cnt1, nE, NSB);
    k_scan1<<<NSB, 512, 0, stream>>>(cnt1, po1, totals, NBLK1);
    k_scat1<<<NBLK1, 1024, 0, stream>>>(src, dst, po1, totals, ebuf, nE, NSB);
    k_sort2<<<NSB, 512, 0, stream>>>(ebuf, totals, col, start, dinv, poff, n, qsz, NSB);

    // ---- layer 1: Pd1 = dinv*(x@W1) [fp16]; h1d = dinv*relu(dinv*Agg(Pd1)+b1)
    k_mm1<<<(n + 63) / 64, 256, 0, stream>>>((const float4*)x, (const float4*)W1,
                                             dinv, Pd1, n);
    k_aggf16<<<g((long long)n * 4), B, 0, stream>>>((const uint2*)Pd1, start, poff,
                                                    col, dinv, b1, (uint2*)h1d, n);

    // ---- layer 2 (agg + mm2 fused): h2d = dinv*relu((dinv*Agg(h1d))@W2+b2)
    k_aggf16_mm2<<<g((long long)n * 4), B, 0, stream>>>((const uint2*)h1d, start,
                                                        poff, col, dinv, W2, b2,
                                                        (uint2*)h2d, n);

    // ---- layer 3 (agg + mm3 fused): h3 = relu((dinv*Agg(h2d))@W3+b3)
    k_aggf32_mm3<<<(int)(((long long)n * 8 + 511) / 512), 512, 0, stream>>>(
        (const uint2*)h2d, start, poff, col, dinv, W3, b3, h3, n);

    // ---- fused mean-pool + head (no atomics; batch is sorted)
    k_poolhead<<<NG, 256, 0, stream>>>(h3, batch, Wl1, bl1, Wl2, bl2, out, n);
}

// Round 17
// 202.245 us; speedup vs baseline: 1.3533x; 1.1361x over previous
//
#include <hip/hip_runtime.h>
#include <hip/hip_fp16.h>

// GCN forward: 3x GCNConv (symmetric norm, self-loops) + mean-pool + MLP head.
// R17: fp16 rows gathered as uint4 (8 halves / 16B per lane-request).
//      R11/12/13/16 triangulation: agg time tracks LANE-REQUEST count
//      (~2 req/cyc/CU), not bytes/lines. TPN 8->4 (agg32), 4->2 (agg16)
//      halves requests; epilogue (still hidden) widens to h[16]/thread.

constexpr int EPA1 = 8192;   // edges per level-1 block
constexpr int NPSB = 256;    // nodes per super-bucket
constexpr int PAD1 = 400;    // [blk][sb] metadata row stride

// ---- fp16 helpers: uint4 = 8 halves
__device__ __forceinline__ void acc8(float4& A, float4& B, uint4 u) {
    __half2* ph = reinterpret_cast<__half2*>(&u);
    float2 f0 = __half22float2(ph[0]);
    float2 f1 = __half22float2(ph[1]);
    float2 f2 = __half22float2(ph[2]);
    float2 f3 = __half22float2(ph[3]);
    A.x += f0.x; A.y += f0.y; A.z += f1.x; A.w += f1.y;
    B.x += f2.x; B.y += f2.y; B.z += f3.x; B.w += f3.y;
}
__device__ __forceinline__ uint4 pack8(const float* h) {
    __half2 a = __floats2half2_rn(h[0], h[1]);
    __half2 b = __floats2half2_rn(h[2], h[3]);
    __half2 c = __floats2half2_rn(h[4], h[5]);
    __half2 d = __floats2half2_rn(h[6], h[7]);
    uint4 u;
    u.x = *reinterpret_cast<unsigned*>(&a);
    u.y = *reinterpret_cast<unsigned*>(&b);
    u.z = *reinterpret_cast<unsigned*>(&c);
    u.w = *reinterpret_cast<unsigned*>(&d);
    return u;
}

// ---- level 1 histogram: per-block super-bucket counts
__global__ __launch_bounds__(1024) void k_hist1(const int* __restrict__ dst,
        int* __restrict__ cnt1, int nE, int NSB) {
    __shared__ int hist[512];
    int t = threadIdx.x;
    if (t < 512) hist[t] = 0;
    __syncthreads();
    int base = blockIdx.x * EPA1, end = min(base + EPA1, nE);
    for (int e = base + t; e < end; e += 1024)
        atomicAdd(&hist[dst[e] >> 8], 1);  // LDS
    __syncthreads();
    if (t < NSB) cnt1[blockIdx.x * PAD1 + t] = hist[t];
}

// ---- level 1 scan: per-sb exclusive prefix over blocks; emits totals
__global__ __launch_bounds__(512) void k_scan1(const int* __restrict__ cnt1,
        int* __restrict__ po1, int* __restrict__ totals, int NBLK1) {
    __shared__ int sc[512];
    int sb = blockIdx.x, t = threadIdx.x;
    int v = (t < NBLK1) ? cnt1[t * PAD1 + sb] : 0;
    sc[t] = v;
    __syncthreads();
    for (int off = 1; off < 512; off <<= 1) {
        int u = (t >= off) ? sc[t - off] : 0;
        __syncthreads();
        sc[t] += u;
        __syncthreads();
    }
    if (t < NBLK1) po1[t * PAD1 + sb] = sc[t] - v;
    if (t == 511) totals[sb] = sc[511];
}

// ---- level 1 scatter: edges -> super-bucket-major ebuf (packed lnode|src).
__global__ __launch_bounds__(1024) void k_scat1(const int* __restrict__ src,
        const int* __restrict__ dst, const int* __restrict__ po1,
        const int* __restrict__ totals, unsigned* __restrict__ ebuf,
        int nE, int NSB) {
    __shared__ int sc[512], cur[512];
    int t = threadIdx.x, blk = blockIdx.x;
    if (t < 512) sc[t] = (t < NSB) ? totals[t] : 0;
    __syncthreads();
    for (int off = 1; off < 512; off <<= 1) {
        int u = (t >= off && t < 512) ? sc[t - off] : 0;
        __syncthreads();
        if (t < 512) sc[t] += u;
        __syncthreads();
    }
    if (t < NSB) cur[t] = (sc[t] - totals[t]) + po1[blk * PAD1 + t];
    __syncthreads();
    int base = blk * EPA1, end = min(base + EPA1, nE);
    for (int e = base + t; e < end; e += 1024) {
        int s = src[e], d = dst[e];
        int pos = atomicAdd(&cur[d >> 8], 1);  // LDS
        ebuf[pos] = ((unsigned)(d & 255) << 17) | (unsigned)s;
    }
}

// ---- level 2: per-sb contiguous counting sort by (node, src-quartile)
__global__ __launch_bounds__(512) void k_sort2(const unsigned* __restrict__ ebuf,
        const int* __restrict__ totals, int* __restrict__ col,
        int* __restrict__ start, float* __restrict__ dinv,
        unsigned* __restrict__ poff, int n, int qsz, int NSB) {
    __shared__ int sc[512];
    __shared__ int hist4[1024], cur4[1024], excl[256];
    int b = blockIdx.x, t = threadIdx.x;
    sc[t] = (t < NSB) ? totals[t] : 0;
    __syncthreads();
    for (int off = 1; off < 512; off <<= 1) {
        int u = (t >= off) ? sc[t - off] : 0;
        __syncthreads();
        sc[t] += u;
        __syncthreads();
    }
    int eend = sc[b], ebase = eend - totals[b];
    hist4[t] = 0; hist4[t + 512] = 0;
    __syncthreads();
    for (int e = ebase + t; e < eend; e += 512) {
        unsigned u = ebuf[e];
        atomicAdd(&hist4[(u >> 17) * 4 + (int)(u & 0x1FFFFu) / qsz], 1);  // LDS
    }
    __syncthreads();
    int c0 = 0, c1 = 0, c2 = 0, c3 = 0, v = 0;
    if (t < 256) {
        c0 = hist4[t * 4];     c1 = hist4[t * 4 + 1];
        c2 = hist4[t * 4 + 2]; c3 = hist4[t * 4 + 3];
        v = c0 + c1 + c2 + c3;
        excl[t] = v;
    }
    __syncthreads();
    for (int off = 1; off < 256; off <<= 1) {
        int u = (t >= off && t < 256) ? excl[t - off] : 0;
        __syncthreads();
        if (t < 256) excl[t] += u;
        __syncthreads();
    }
    if (t < 256) {
        int sbase = ebase + excl[t] - v;
        cur4[t * 4]     = sbase;
        cur4[t * 4 + 1] = sbase + c0;
        cur4[t * 4 + 2] = sbase + c0 + c1;
        cur4[t * 4 + 3] = sbase + c0 + c1 + c2;
        int node = (b << 8) + t;
        if (node < n) {
            start[node] = sbase;
            dinv[node] = rsqrtf((float)(v + 1));
            poff[node] = (unsigned)c0 | ((unsigned)c1 << 8) |
                         ((unsigned)c2 << 16) | ((unsigned)c3 << 24);
        }
    }
    __syncthreads();
    for (int e = ebase + t; e < eend; e += 512) {
        unsigned u = ebuf[e];
        int s = (int)(u & 0x1FFFFu);
        int pos = atomicAdd(&cur4[(u >> 17) * 4 + s / qsz], 1);  // LDS
        col[pos] = s;
    }
}

// ---- fp16 gather body: uint4 (8 halves) per lane-request; quartile phases
//      preserved; unroll-4 keeps 4x16B in flight. U4PR = uint4s per row.
template <int U4PR>
__device__ __forceinline__ void agg_gather8(const uint4* __restrict__ T,
        const int* __restrict__ col, int base, unsigned pk, int q,
        size_t selfIdx, float4& A, float4& B) {
    A = make_float4(0.f, 0.f, 0.f, 0.f);
    B = make_float4(0.f, 0.f, 0.f, 0.f);
    acc8(A, B, T[selfIdx]);  // self term
    #pragma unroll
    for (int p = 0; p < 4; ++p) {
        int len = (int)((pk >> (8 * p)) & 255u);
        int k = 0;
        for (; k + 4 <= len; k += 4) {
            uint4 u0 = T[(size_t)col[base + k]     * U4PR + q];
            uint4 u1 = T[(size_t)col[base + k + 1] * U4PR + q];
            uint4 u2 = T[(size_t)col[base + k + 2] * U4PR + q];
            uint4 u3 = T[(size_t)col[base + k + 3] * U4PR + q];
            acc8(A, B, u0); acc8(A, B, u1); acc8(A, B, u2); acc8(A, B, u3);
        }
        for (; k < len; ++k)
            acc8(A, B, T[(size_t)col[base + k] * U4PR + q]);
        base += len;
    }
}

// ---- layer-1 agg (F=16, TPN=2): h1d = dinv*relu(dinv*Agg(Pd1)+b1)
__global__ void k_aggf16(const uint4* __restrict__ T, const int* __restrict__ start,
        const unsigned* __restrict__ poff, const int* __restrict__ col,
        const float* __restrict__ dinv, const float* __restrict__ bias,
        uint4* __restrict__ out, int n) {
    int idx = blockIdx.x * blockDim.x + threadIdx.x;
    int i = idx / 2, q = idx % 2;
    if (i >= n) return;
    float4 A, B;
    agg_gather8<2>(T, col, start[i], poff[i], q, (size_t)i * 2 + q, A, B);
    float d = dinv[i];
    float4 bA = ((const float4*)bias)[q * 2];
    float4 bB = ((const float4*)bias)[q * 2 + 1];
    float h[8];
    h[0] = d * fmaxf(d * A.x + bA.x, 0.0f);
    h[1] = d * fmaxf(d * A.y + bA.y, 0.0f);
    h[2] = d * fmaxf(d * A.z + bA.z, 0.0f);
    h[3] = d * fmaxf(d * A.w + bA.w, 0.0f);
    h[4] = d * fmaxf(d * B.x + bB.x, 0.0f);
    h[5] = d * fmaxf(d * B.y + bB.y, 0.0f);
    h[6] = d * fmaxf(d * B.z + bB.z, 0.0f);
    h[7] = d * fmaxf(d * B.w + bB.w, 0.0f);
    out[(size_t)i * 2 + q] = pack8(h);
}

// ---- layer-2 agg fused with mm2 (F=16, TPN=2): 2-lane shfl groups, h[16].
__global__ __launch_bounds__(256) void k_aggf16_mm2(const uint4* __restrict__ T,
        const int* __restrict__ start, const unsigned* __restrict__ poff,
        const int* __restrict__ col, const float* __restrict__ dinv,
        const float* __restrict__ W2, const float* __restrict__ b2,
        uint4* __restrict__ out, int n) {
    __shared__ float sW[16 * 32];
    __shared__ float sB[32];
    int t = threadIdx.x;
    for (int j = t; j < 512; j += 256) sW[j] = W2[j];
    if (t < 32) sB[t] = b2[t];
    __syncthreads();
    int idx = blockIdx.x * blockDim.x + t;
    int i = idx / 2, q = idx % 2;
    if (i >= n) return;
    float4 A, B;
    agg_gather8<2>(T, col, start[i], poff[i], q, (size_t)i * 2 + q, A, B);
    float d = dinv[i];
    float a[8] = {d * A.x, d * A.y, d * A.z, d * A.w,
                  d * B.x, d * B.y, d * B.z, d * B.w};  // a1 fragment (8 of 16)
    int lane = t & 63;
    int gbase = lane & ~1;  // 2-lane group
    float h[16];
    #pragma unroll
    for (int o = 0; o < 16; ++o) h[o] = sB[q * 16 + o];
    #pragma unroll
    for (int j = 0; j < 2; ++j) {
        #pragma unroll
        for (int kk = 0; kk < 8; ++kk) {
            float ak = __shfl(a[kk], gbase + j);
            const float* w0 = &sW[(j * 8 + kk) * 32 + q * 16];
            #pragma unroll
            for (int o = 0; o < 16; ++o) h[o] += ak * w0[o];
        }
    }
    float ho[16];
    #pragma unroll
    for (int o = 0; o < 16; ++o) ho[o] = d * fmaxf(h[o], 0.0f);
    out[(size_t)i * 4 + q * 2]     = pack8(ho);
    out[(size_t)i * 4 + q * 2 + 1] = pack8(ho + 8);
}

// ---- layer-3 agg fused with mm3 (F=32, TPN=4): 4-lane shfl groups, h[16].
__global__ __launch_bounds__(512) void k_aggf32_mm3(const uint4* __restrict__ T,
        const int* __restrict__ start, const unsigned* __restrict__ poff,
        const int* __restrict__ col, const float* __restrict__ dinv,
        const float* __restrict__ W3, const float* __restrict__ b3,
        float* __restrict__ out, int n) {
    __shared__ float sW[32 * 64];
    __shared__ float sB[64];
    int t = threadIdx.x;
    for (int j = t; j < 2048; j += 512) sW[j] = W3[j];
    if (t < 64) sB[t] = b3[t];
    __syncthreads();
    int idx = blockIdx.x * blockDim.x + t;
    int i = idx / 4, q = idx % 4;
    if (i >= n) return;
    float4 A, B;
    agg_gather8<4>(T, col, start[i], poff[i], q, (size_t)i * 4 + q, A, B);
    float d = dinv[i];
    float a[8] = {d * A.x, d * A.y, d * A.z, d * A.w,
                  d * B.x, d * B.y, d * B.z, d * B.w};  // a2 fragment (8 of 32)
    int lane = t & 63;
    int gbase = lane & ~3;  // 4-lane group
    float h[16];
    #pragma unroll
    for (int o = 0; o < 16; ++o) h[o] = sB[q * 16 + o];
    #pragma unroll
    for (int j = 0; j < 4; ++j) {
        #pragma unroll
        for (int kk = 0; kk < 8; ++kk) {
            float ak = __shfl(a[kk], gbase + j);
            const float* w0 = &sW[(j * 8 + kk) * 64 + q * 16];
            #pragma unroll
            for (int o = 0; o < 16; ++o) h[o] += ak * w0[o];
        }
    }
    float4* O4 = (float4*)out;
    float4 o0, o1, o2, o3;
    o0.x = fmaxf(h[0], 0.f);  o0.y = fmaxf(h[1], 0.f);
    o0.z = fmaxf(h[2], 0.f);  o0.w = fmaxf(h[3], 0.f);
    o1.x = fmaxf(h[4], 0.f);  o1.y = fmaxf(h[5], 0.f);
    o1.z = fmaxf(h[6], 0.f);  o1.w = fmaxf(h[7], 0.f);
    o2.x = fmaxf(h[8], 0.f);  o2.y = fmaxf(h[9], 0.f);
    o2.z = fmaxf(h[10], 0.f); o2.w = fmaxf(h[11], 0.f);
    o3.x = fmaxf(h[12], 0.f); o3.y = fmaxf(h[13], 0.f);
    o3.z = fmaxf(h[14], 0.f); o3.w = fmaxf(h[15], 0.f);
    size_t rb = (size_t)i * 16 + q * 4;
    O4[rb] = o0; O4[rb + 1] = o1; O4[rb + 2] = o2; O4[rb + 3] = o3;
}

// ---- mm1: Pd1 (fp16) = dinv * (x @ W1), K=128 F=16. LDS-tiled.
__global__ __launch_bounds__(256) void k_mm1(const float4* __restrict__ X4,
        const float4* __restrict__ W4, const float* __restrict__ dinv,
        __half* __restrict__ out, int n) {
    __shared__ float4 xs[64 * 32];
    __shared__ float4 ws[512];
    int t = threadIdx.x;
    int nb = blockIdx.x * 64;
    ws[t] = W4[t]; ws[t + 256] = W4[t + 256];
    int lim = min(64, n - nb);
    #pragma unroll
    for (int it = 0; it < 8; ++it) {
        int idx = it * 256 + t;
        if ((idx >> 5) < lim) xs[idx] = X4[(size_t)nb * 32 + idx];
    }
    __syncthreads();
    int lane = t & 63, wv = t >> 6;
    int f = lane & 15, kc = lane >> 4;
    float wcol[32];
    #pragma unroll
    for (int kk = 0; kk < 32; ++kk)
        wcol[kk] = ((const float*)ws)[(kc * 32 + kk) * 16 + f];
    for (int ln = wv * 16; ln < wv * 16 + 16; ++ln) {
        if (ln >= lim) break;
        int i = nb + ln;
        float acc = 0.0f;
        #pragma unroll
        for (int j = 0; j < 8; ++j) {
            float4 hv = xs[ln * 32 + kc * 8 + j];
            acc += hv.x * wcol[4 * j]     + hv.y * wcol[4 * j + 1]
                 + hv.z * wcol[4 * j + 2] + hv.w * wcol[4 * j + 3];
        }
        acc += __shfl_xor(acc, 16);
        acc += __shfl_xor(acc, 32);
        if (kc == 0) out[(size_t)i * 16 + f] = __float2half_rn(acc * dinv[i]);
    }
}

// ---- fused mean-pool + MLP head: 256 threads per graph (4-way row parallel)
__global__ __launch_bounds__(256) void k_poolhead(const float* __restrict__ h3,
        const int* __restrict__ batch, const float* __restrict__ Wl1,
        const float* __restrict__ bl1, const float* __restrict__ Wl2,
        const float* __restrict__ bl2, float* __restrict__ out, int n) {
    int g = blockIdx.x, t = threadIdx.x;
    int f = t & 63, r = t >> 6;
    __shared__ int sb[2];
    __shared__ float part[4][64];
    __shared__ float mean[64], hid[64];
    if (t < 2) {
        int target = g + t;
        int lo = 0, hi = n;
        while (lo < hi) {
            int mid = (lo + hi) >> 1;
            if (batch[mid] < target) lo = mid + 1; else hi = mid;
        }
        sb[t] = lo;
    }
    __syncthreads();
    int s = sb[0], e = sb[1];
    float acc = 0.0f;
    for (int i = s + r; i < e; i += 4) acc += h3[(size_t)i * 64 + f];
    part[r][f] = acc;
    __syncthreads();
    if (t < 64) {
        float c = fmaxf((float)(e - s), 1.0f);
        mean[t] = (part[0][t] + part[1][t] + part[2][t] + part[3][t]) / c;
    }
    __syncthreads();
    if (t < 64) {
        float a = bl1[t];
        #pragma unroll 8
        for (int k = 0; k < 64; ++k) a += mean[k] * Wl1[k * 64 + t];
        hid[t] = fmaxf(a, 0.0f);
    }
    __syncthreads();
    if (t < 2) {
        float o = bl2[t];
        #pragma unroll 8
        for (int k = 0; k < 64; ++k) o += hid[k] * Wl2[k * 2 + t];
        out[g * 2 + t] = o;
    }
}

extern "C" void kernel_launch(void* const* d_in, const int* in_sizes, int n_in,
                              void* d_out, int out_size, void* d_ws, size_t ws_size,
                              hipStream_t stream) {
    const float* x    = (const float*)d_in[0];
    const int*   ei   = (const int*)d_in[1];
    const int*   batch= (const int*)d_in[2];
    const float* W1   = (const float*)d_in[3];
    const float* b1   = (const float*)d_in[4];
    const float* W2   = (const float*)d_in[5];
    const float* b2   = (const float*)d_in[6];
    const float* W3   = (const float*)d_in[7];
    const float* b3   = (const float*)d_in[8];
    const float* Wl1  = (const float*)d_in[9];
    const float* bl1  = (const float*)d_in[10];
    const float* Wl2  = (const float*)d_in[11];
    const float* bl2  = (const float*)d_in[12];
    float* out = (float*)d_out;

    const int n  = in_sizes[2];      // 100000
    const int nE = in_sizes[1] / 2;  // 3200000
    const int* src = ei;
    const int* dst = ei + nE;

    const int NSB   = (n + NPSB - 1) / NPSB;   // 391 super-buckets (256 nodes)
    const int NBLK1 = (nE + EPA1 - 1) / EPA1;  // 391 level-1 blocks
    const int NG    = 1024;
    const int qsz   = (n + 3) / 4;             // src-quartile size

    char* w = (char*)d_ws;
    auto alloc_f = [&](size_t cnt) { float* p = (float*)w; w += cnt * 4; return p; };
    auto alloc_i = [&](size_t cnt) { int*   p = (int*)w;   w += cnt * 4; return p; };
    auto alloc_h = [&](size_t cnt) { __half* p = (__half*)w; w += cnt * 2; return p; };

    float*    dinv   = alloc_f(n);
    int*      start  = alloc_i(n);
    unsigned* poff   = (unsigned*)alloc_i(n);
    int*      cnt1   = alloc_i((size_t)NBLK1 * PAD1);
    int*      po1    = alloc_i((size_t)NBLK1 * PAD1);
    int*      totals = alloc_i(512);
    unsigned* ebuf   = (unsigned*)alloc_i(nE);   // 12.8 MB
    int*      col    = alloc_i(nE);              // 12.8 MB
    __half* Pd1 = alloc_h((size_t)n * 16);  // 3.2 MB fp16
    __half* h1d = alloc_h((size_t)n * 16);  // 3.2 MB fp16
    __half* h2d = alloc_h((size_t)n * 32);  // 6.4 MB fp16
    float*  h3  = alloc_f((size_t)n * 64);  // f32 (feeds poolhead)

    const int B = 256;
    auto g = [&](long long t) { return (int)((t + B - 1) / B); };

    // ---- CSR build: two-level radix, zero global atomics
    k_hist1<<<NBLK1, 1024, 0, stream>>>(dst, cnt1, nE, NSB);
    k_scan1<<<NSB, 512, 0, stream>>>(cnt1, po1, totals, NBLK1);
    k_scat1<<<NBLK1, 1024, 0, stream>>>(src, dst, po1, totals, ebuf, nE, NSB);
    k_sort2<<<NSB, 512, 0, stream>>>(ebuf, totals, col, start, dinv, poff, n, qsz, NSB);

    // ---- layer 1: Pd1 = dinv*(x@W1) [fp16]; h1d = dinv*relu(dinv*Agg(Pd1)+b1)
    k_mm1<<<(n + 63) / 64, 256, 0, stream>>>((const float4*)x, (const float4*)W1,
                                             dinv, Pd1, n);
    k_aggf16<<<g((long long)n * 2), B, 0, stream>>>((const uint4*)Pd1, start, poff,
                                                    col, dinv, b1, (uint4*)h1d, n);

    // ---- layer 2 (agg + mm2 fused): h2d = dinv*relu((dinv*Agg(h1d))@W2+b2)
    k_aggf16_mm2<<<g((long long)n * 2), B, 0, stream>>>((const uint4*)h1d, start,
                                                        poff, col, dinv, W2, b2,
                                                        (uint4*)h2d, n);

    // ---- layer 3 (agg + mm3 fused): h3 = relu((dinv*Agg(h2d))@W3+b3)
    k_aggf32_mm3<<<(int)(((long long)n * 4 + 511) / 512), 512, 0, stream>>>(
        (const uint4*)h2d, start, poff, col, dinv, W3, b3, h3, n);

    // ---- fused mean-pool + head (no atomics; batch is sorted)
    k_poolhead<<<NG, 256, 0, stream>>>(h3, batch, Wl1, bl1, Wl2, bl2, out, n);
}

// Round 18
// 197.622 us; speedup vs baseline: 1.3849x; 1.0234x over previous
//
#include <hip/hip_runtime.h>
#include <hip/hip_fp16.h>

// GCN forward: 3x GCNConv (symmetric norm, self-loops) + mean-pool + MLP head.
// R18: split-K gather — each node's edge list split across 2 lane-groups
//      (quartiles {0,1} vs {2,3}), partials merged with one shfl_xor.
//      2x waves, half the per-thread miss chain, zero extra global traffic.
//      (R17: agg latency-bound at 42% occupancy, 782-block grid.)
//      + magic-mul division in sort2.

constexpr int EPA1 = 8192;   // edges per level-1 block
constexpr int NPSB = 256;    // nodes per super-bucket
constexpr int PAD1 = 400;    // [blk][sb] metadata row stride

// ---- fp16 helpers: uint4 = 8 halves
__device__ __forceinline__ void acc8(float4& A, float4& B, uint4 u) {
    __half2* ph = reinterpret_cast<__half2*>(&u);
    float2 f0 = __half22float2(ph[0]);
    float2 f1 = __half22float2(ph[1]);
    float2 f2 = __half22float2(ph[2]);
    float2 f3 = __half22float2(ph[3]);
    A.x += f0.x; A.y += f0.y; A.z += f1.x; A.w += f1.y;
    B.x += f2.x; B.y += f2.y; B.z += f3.x; B.w += f3.y;
}
__device__ __forceinline__ uint4 pack8(const float* h) {
    __half2 a = __floats2half2_rn(h[0], h[1]);
    __half2 b = __floats2half2_rn(h[2], h[3]);
    __half2 c = __floats2half2_rn(h[4], h[5]);
    __half2 d = __floats2half2_rn(h[6], h[7]);
    uint4 u;
    u.x = *reinterpret_cast<unsigned*>(&a);
    u.y = *reinterpret_cast<unsigned*>(&b);
    u.z = *reinterpret_cast<unsigned*>(&c);
    u.w = *reinterpret_cast<unsigned*>(&d);
    return u;
}

// ---- level 1 histogram: per-block super-bucket counts
__global__ __launch_bounds__(1024) void k_hist1(const int* __restrict__ dst,
        int* __restrict__ cnt1, int nE, int NSB) {
    __shared__ int hist[512];
    int t = threadIdx.x;
    if (t < 512) hist[t] = 0;
    __syncthreads();
    int base = blockIdx.x * EPA1, end = min(base + EPA1, nE);
    for (int e = base + t; e < end; e += 1024)
        atomicAdd(&hist[dst[e] >> 8], 1);  // LDS
    __syncthreads();
    if (t < NSB) cnt1[blockIdx.x * PAD1 + t] = hist[t];
}

// ---- level 1 scan: per-sb exclusive prefix over blocks; emits totals
__global__ __launch_bounds__(512) void k_scan1(const int* __restrict__ cnt1,
        int* __restrict__ po1, int* __restrict__ totals, int NBLK1) {
    __shared__ int sc[512];
    int sb = blockIdx.x, t = threadIdx.x;
    int v = (t < NBLK1) ? cnt1[t * PAD1 + sb] : 0;
    sc[t] = v;
    __syncthreads();
    for (int off = 1; off < 512; off <<= 1) {
        int u = (t >= off) ? sc[t - off] : 0;
        __syncthreads();
        sc[t] += u;
        __syncthreads();
    }
    if (t < NBLK1) po1[t * PAD1 + sb] = sc[t] - v;
    if (t == 511) totals[sb] = sc[511];
}

// ---- level 1 scatter: edges -> super-bucket-major ebuf (packed lnode|src).
__global__ __launch_bounds__(1024) void k_scat1(const int* __restrict__ src,
        const int* __restrict__ dst, const int* __restrict__ po1,
        const int* __restrict__ totals, unsigned* __restrict__ ebuf,
        int nE, int NSB) {
    __shared__ int sc[512], cur[512];
    int t = threadIdx.x, blk = blockIdx.x;
    if (t < 512) sc[t] = (t < NSB) ? totals[t] : 0;
    __syncthreads();
    for (int off = 1; off < 512; off <<= 1) {
        int u = (t >= off && t < 512) ? sc[t - off] : 0;
        __syncthreads();
        if (t < 512) sc[t] += u;
        __syncthreads();
    }
    if (t < NSB) cur[t] = (sc[t] - totals[t]) + po1[blk * PAD1 + t];
    __syncthreads();
    int base = blk * EPA1, end = min(base + EPA1, nE);
    for (int e = base + t; e < end; e += 1024) {
        int s = src[e], d = dst[e];
        int pos = atomicAdd(&cur[d >> 8], 1);  // LDS
        ebuf[pos] = ((unsigned)(d & 255) << 17) | (unsigned)s;
    }
}

// ---- level 2: per-sb contiguous counting sort by (node, src-quartile)
__global__ __launch_bounds__(512) void k_sort2(const unsigned* __restrict__ ebuf,
        const int* __restrict__ totals, int* __restrict__ col,
        int* __restrict__ start, float* __restrict__ dinv,
        unsigned* __restrict__ poff, int n, unsigned qmagic, int NSB) {
    __shared__ int sc[512];
    __shared__ int hist4[1024], cur4[1024], excl[256];
    int b = blockIdx.x, t = threadIdx.x;
    sc[t] = (t < NSB) ? totals[t] : 0;
    __syncthreads();
    for (int off = 1; off < 512; off <<= 1) {
        int u = (t >= off) ? sc[t - off] : 0;
        __syncthreads();
        sc[t] += u;
        __syncthreads();
    }
    int eend = sc[b], ebase = eend - totals[b];
    hist4[t] = 0; hist4[t + 512] = 0;
    __syncthreads();
    for (int e = ebase + t; e < eend; e += 512) {
        unsigned u = ebuf[e];
        unsigned s = u & 0x1FFFFu;
        atomicAdd(&hist4[(u >> 17) * 4 + __umulhi(s, qmagic)], 1);  // LDS
    }
    __syncthreads();
    int c0 = 0, c1 = 0, c2 = 0, c3 = 0, v = 0;
    if (t < 256) {
        c0 = hist4[t * 4];     c1 = hist4[t * 4 + 1];
        c2 = hist4[t * 4 + 2]; c3 = hist4[t * 4 + 3];
        v = c0 + c1 + c2 + c3;
        excl[t] = v;
    }
    __syncthreads();
    for (int off = 1; off < 256; off <<= 1) {
        int u = (t >= off && t < 256) ? excl[t - off] : 0;
        __syncthreads();
        if (t < 256) excl[t] += u;
        __syncthreads();
    }
    if (t < 256) {
        int sbase = ebase + excl[t] - v;
        cur4[t * 4]     = sbase;
        cur4[t * 4 + 1] = sbase + c0;
        cur4[t * 4 + 2] = sbase + c0 + c1;
        cur4[t * 4 + 3] = sbase + c0 + c1 + c2;
        int node = (b << 8) + t;
        if (node < n) {
            start[node] = sbase;
            dinv[node] = rsqrtf((float)(v + 1));
            poff[node] = (unsigned)c0 | ((unsigned)c1 << 8) |
                         ((unsigned)c2 << 16) | ((unsigned)c3 << 24);
        }
    }
    __syncthreads();
    for (int e = ebase + t; e < eend; e += 512) {
        unsigned u = ebuf[e];
        unsigned s = u & 0x1FFFFu;
        int pos = atomicAdd(&cur4[(u >> 17) * 4 + __umulhi(s, qmagic)], 1);  // LDS
        col[pos] = (int)s;
    }
}

// ---- half-gather: quartiles [p0, p0+2); base pre-adjusted to quartile p0.
//      Self term handled by caller (h==0 group only).
template <int U4PR>
__device__ __forceinline__ void agg_gather_half(const uint4* __restrict__ T,
        const int* __restrict__ col, int base, unsigned pk, int p0, int q,
        float4& A, float4& B) {
    #pragma unroll
    for (int pp = 0; pp < 2; ++pp) {
        int len = (int)((pk >> (8 * (p0 + pp))) & 255u);
        int k = 0;
        for (; k + 4 <= len; k += 4) {
            uint4 u0 = T[(size_t)col[base + k]     * U4PR + q];
            uint4 u1 = T[(size_t)col[base + k + 1] * U4PR + q];
            uint4 u2 = T[(size_t)col[base + k + 2] * U4PR + q];
            uint4 u3 = T[(size_t)col[base + k + 3] * U4PR + q];
            acc8(A, B, u0); acc8(A, B, u1); acc8(A, B, u2); acc8(A, B, u3);
        }
        for (; k < len; ++k)
            acc8(A, B, T[(size_t)col[base + k] * U4PR + q]);
        base += len;
    }
}
__device__ __forceinline__ void combine(float4& A, float4& B, int xorMask) {
    A.x += __shfl_xor(A.x, xorMask); A.y += __shfl_xor(A.y, xorMask);
    A.z += __shfl_xor(A.z, xorMask); A.w += __shfl_xor(A.w, xorMask);
    B.x += __shfl_xor(B.x, xorMask); B.y += __shfl_xor(B.y, xorMask);
    B.z += __shfl_xor(B.z, xorMask); B.w += __shfl_xor(B.w, xorMask);
}

// ---- layer-1 agg (F=16, 4 lanes/node: q=sub&1, h=sub>>1)
__global__ void k_aggf16(const uint4* __restrict__ T, const int* __restrict__ start,
        const unsigned* __restrict__ poff, const int* __restrict__ col,
        const float* __restrict__ dinv, const float* __restrict__ bias,
        uint4* __restrict__ out, int n) {
    int idx = blockIdx.x * blockDim.x + threadIdx.x;
    int i = idx >> 2, sub = idx & 3;
    if (i >= n) return;
    int q = sub & 1, h = sub >> 1;
    unsigned pk = poff[i];
    int len01 = (int)(pk & 255u) + (int)((pk >> 8) & 255u);
    int base = start[i] + (h ? len01 : 0);
    float4 A = make_float4(0.f, 0.f, 0.f, 0.f);
    float4 B = make_float4(0.f, 0.f, 0.f, 0.f);
    if (h == 0) acc8(A, B, T[(size_t)i * 2 + q]);  // self term once
    agg_gather_half<2>(T, col, base, pk, h * 2, q, A, B);
    combine(A, B, 2);
    if (h) return;
    float d = dinv[i];
    float4 bA = ((const float4*)bias)[q * 2];
    float4 bB = ((const float4*)bias)[q * 2 + 1];
    float ho[8];
    ho[0] = d * fmaxf(d * A.x + bA.x, 0.0f);
    ho[1] = d * fmaxf(d * A.y + bA.y, 0.0f);
    ho[2] = d * fmaxf(d * A.z + bA.z, 0.0f);
    ho[3] = d * fmaxf(d * A.w + bA.w, 0.0f);
    ho[4] = d * fmaxf(d * B.x + bB.x, 0.0f);
    ho[5] = d * fmaxf(d * B.y + bB.y, 0.0f);
    ho[6] = d * fmaxf(d * B.z + bB.z, 0.0f);
    ho[7] = d * fmaxf(d * B.w + bB.w, 0.0f);
    out[(size_t)i * 2 + q] = pack8(ho);
}

// ---- layer-2 agg + mm2 (F=16, 4 lanes/node): all 4 lanes run the epilogue.
__global__ __launch_bounds__(256) void k_aggf16_mm2(const uint4* __restrict__ T,
        const int* __restrict__ start, const unsigned* __restrict__ poff,
        const int* __restrict__ col, const float* __restrict__ dinv,
        const float* __restrict__ W2, const float* __restrict__ b2,
        uint4* __restrict__ out, int n) {
    __shared__ float sW[16 * 32];
    __shared__ float sB[32];
    int t = threadIdx.x;
    for (int j = t; j < 512; j += 256) sW[j] = W2[j];
    if (t < 32) sB[t] = b2[t];
    __syncthreads();
    int idx = blockIdx.x * blockDim.x + t;
    int i = idx >> 2, sub = idx & 3;
    if (i >= n) return;
    int q = sub & 1, h = sub >> 1;
    unsigned pk = poff[i];
    int len01 = (int)(pk & 255u) + (int)((pk >> 8) & 255u);
    int base = start[i] + (h ? len01 : 0);
    float4 A = make_float4(0.f, 0.f, 0.f, 0.f);
    float4 B = make_float4(0.f, 0.f, 0.f, 0.f);
    if (h == 0) acc8(A, B, T[(size_t)i * 2 + q]);
    agg_gather_half<2>(T, col, base, pk, h * 2, q, A, B);
    combine(A, B, 2);
    float d = dinv[i];
    float a[8] = {d * A.x, d * A.y, d * A.z, d * A.w,
                  d * B.x, d * B.y, d * B.z, d * B.w};  // a1 frag for uint4 q
    int lane = t & 63;
    int gbase = lane & ~3;  // 4-lane group
    float hacc[8];
    #pragma unroll
    for (int o = 0; o < 8; ++o) hacc[o] = sB[sub * 8 + o];
    #pragma unroll
    for (int j = 0; j < 2; ++j) {
        #pragma unroll
        for (int kk = 0; kk < 8; ++kk) {
            float ak = __shfl(a[kk], gbase + j);  // lane sub=j holds frag q=j
            const float* w0 = &sW[(j * 8 + kk) * 32 + sub * 8];
            #pragma unroll
            for (int o = 0; o < 8; ++o) hacc[o] += ak * w0[o];
        }
    }
    float ho[8];
    #pragma unroll
    for (int o = 0; o < 8; ++o) ho[o] = d * fmaxf(hacc[o], 0.0f);
    out[(size_t)i * 4 + sub] = pack8(ho);
}

// ---- layer-3 agg + mm3 (F=32, 8 lanes/node: q=sub&3, h=sub>>2).
__global__ __launch_bounds__(512) void k_aggf32_mm3(const uint4* __restrict__ T,
        const int* __restrict__ start, const unsigned* __restrict__ poff,
        const int* __restrict__ col, const float* __restrict__ dinv,
        const float* __restrict__ W3, const float* __restrict__ b3,
        float* __restrict__ out, int n) {
    __shared__ float sW[32 * 64];
    __shared__ float sB[64];
    int t = threadIdx.x;
    for (int j = t; j < 2048; j += 512) sW[j] = W3[j];
    if (t < 64) sB[t] = b3[t];
    __syncthreads();
    int idx = blockIdx.x * blockDim.x + t;
    int i = idx >> 3, sub = idx & 7;
    if (i >= n) return;
    int q = sub & 3, h = sub >> 2;
    unsigned pk = poff[i];
    int len01 = (int)(pk & 255u) + (int)((pk >> 8) & 255u);
    int base = start[i] + (h ? len01 : 0);
    float4 A = make_float4(0.f, 0.f, 0.f, 0.f);
    float4 B = make_float4(0.f, 0.f, 0.f, 0.f);
    if (h == 0) acc8(A, B, T[(size_t)i * 4 + q]);
    agg_gather_half<4>(T, col, base, pk, h * 2, q, A, B);
    combine(A, B, 4);
    float d = dinv[i];
    float a[8] = {d * A.x, d * A.y, d * A.z, d * A.w,
                  d * B.x, d * B.y, d * B.z, d * B.w};  // a2 frag for uint4 q
    int lane = t & 63;
    int gbase = lane & ~7;  // 8-lane group
    float hacc[8];
    #pragma unroll
    for (int o = 0; o < 8; ++o) hacc[o] = sB[sub * 8 + o];
    #pragma unroll
    for (int j = 0; j < 4; ++j) {
        #pragma unroll
        for (int kk = 0; kk < 8; ++kk) {
            float ak = __shfl(a[kk], gbase + j);  // lane sub=j holds frag q=j
            const float* w0 = &sW[(j * 8 + kk) * 64 + sub * 8];
            #pragma unroll
            for (int o = 0; o < 8; ++o) hacc[o] += ak * w0[o];
        }
    }
    float4 o0, o1;
    o0.x = fmaxf(hacc[0], 0.f); o0.y = fmaxf(hacc[1], 0.f);
    o0.z = fmaxf(hacc[2], 0.f); o0.w = fmaxf(hacc[3], 0.f);
    o1.x = fmaxf(hacc[4], 0.f); o1.y = fmaxf(hacc[5], 0.f);
    o1.z = fmaxf(hacc[6], 0.f); o1.w = fmaxf(hacc[7], 0.f);
    float4* O4 = (float4*)out;
    size_t rb = (size_t)i * 16 + sub * 2;
    O4[rb] = o0; O4[rb + 1] = o1;
}

// ---- mm1: Pd1 (fp16) = dinv * (x @ W1), K=128 F=16. LDS-tiled.
__global__ __launch_bounds__(256) void k_mm1(const float4* __restrict__ X4,
        const float4* __restrict__ W4, const float* __restrict__ dinv,
        __half* __restrict__ out, int n) {
    __shared__ float4 xs[64 * 32];
    __shared__ float4 ws[512];
    int t = threadIdx.x;
    int nb = blockIdx.x * 64;
    ws[t] = W4[t]; ws[t + 256] = W4[t + 256];
    int lim = min(64, n - nb);
    #pragma unroll
    for (int it = 0; it < 8; ++it) {
        int idx = it * 256 + t;
        if ((idx >> 5) < lim) xs[idx] = X4[(size_t)nb * 32 + idx];
    }
    __syncthreads();
    int lane = t & 63, wv = t >> 6;
    int f = lane & 15, kc = lane >> 4;
    float wcol[32];
    #pragma unroll
    for (int kk = 0; kk < 32; ++kk)
        wcol[kk] = ((const float*)ws)[(kc * 32 + kk) * 16 + f];
    for (int ln = wv * 16; ln < wv * 16 + 16; ++ln) {
        if (ln >= lim) break;
        int i = nb + ln;
        float acc = 0.0f;
        #pragma unroll
        for (int j = 0; j < 8; ++j) {
            float4 hv = xs[ln * 32 + kc * 8 + j];
            acc += hv.x * wcol[4 * j]     + hv.y * wcol[4 * j + 1]
                 + hv.z * wcol[4 * j + 2] + hv.w * wcol[4 * j + 3];
        }
        acc += __shfl_xor(acc, 16);
        acc += __shfl_xor(acc, 32);
        if (kc == 0) out[(size_t)i * 16 + f] = __float2half_rn(acc * dinv[i]);
    }
}

// ---- fused mean-pool + MLP head: 256 threads per graph (4-way row parallel)
__global__ __launch_bounds__(256) void k_poolhead(const float* __restrict__ h3,
        const int* __restrict__ batch, const float* __restrict__ Wl1,
        const float* __restrict__ bl1, const float* __restrict__ Wl2,
        const float* __restrict__ bl2, float* __restrict__ out, int n) {
    int g = blockIdx.x, t = threadIdx.x;
    int f = t & 63, r = t >> 6;
    __shared__ int sb[2];
    __shared__ float part[4][64];
    __shared__ float mean[64], hid[64];
    if (t < 2) {
        int target = g + t;
        int lo = 0, hi = n;
        while (lo < hi) {
            int mid = (lo + hi) >> 1;
            if (batch[mid] < target) lo = mid + 1; else hi = mid;
        }
        sb[t] = lo;
    }
    __syncthreads();
    int s = sb[0], e = sb[1];
    float acc = 0.0f;
    for (int i = s + r; i < e; i += 4) acc += h3[(size_t)i * 64 + f];
    part[r][f] = acc;
    __syncthreads();
    if (t < 64) {
        float c = fmaxf((float)(e - s), 1.0f);
        mean[t] = (part[0][t] + part[1][t] + part[2][t] + part[3][t]) / c;
    }
    __syncthreads();
    if (t < 64) {
        float a = bl1[t];
        #pragma unroll 8
        for (int k = 0; k < 64; ++k) a += mean[k] * Wl1[k * 64 + t];
        hid[t] = fmaxf(a, 0.0f);
    }
    __syncthreads();
    if (t < 2) {
        float o = bl2[t];
        #pragma unroll 8
        for (int k = 0; k < 64; ++k) o += hid[k] * Wl2[k * 2 + t];
        out[g * 2 + t] = o;
    }
}

extern "C" void kernel_launch(void* const* d_in, const int* in_sizes, int n_in,
                              void* d_out, int out_size, void* d_ws, size_t ws_size,
                              hipStream_t stream) {
    const float* x    = (const float*)d_in[0];
    const int*   ei   = (const int*)d_in[1];
    const int*   batch= (const int*)d_in[2];
    const float* W1   = (const float*)d_in[3];
    const float* b1   = (const float*)d_in[4];
    const float* W2   = (const float*)d_in[5];
    const float* b2   = (const float*)d_in[6];
    const float* W3   = (const float*)d_in[7];
    const float* b3   = (const float*)d_in[8];
    const float* Wl1  = (const float*)d_in[9];
    const float* bl1  = (const float*)d_in[10];
    const float* Wl2  = (const float*)d_in[11];
    const float* bl2  = (const float*)d_in[12];
    float* out = (float*)d_out;

    const int n  = in_sizes[2];      // 100000
    const int nE = in_sizes[1] / 2;  // 3200000
    const int* src = ei;
    const int* dst = ei + nE;

    const int NSB   = (n + NPSB - 1) / NPSB;   // 391 super-buckets (256 nodes)
    const int NBLK1 = (nE + EPA1 - 1) / EPA1;  // 391 level-1 blocks
    const int NG    = 1024;
    const int qsz   = (n + 3) / 4;             // src-quartile size
    const unsigned qmagic = (unsigned)((0x100000000ULL + qsz - 1) / qsz);

    char* w = (char*)d_ws;
    auto alloc_f = [&](size_t cnt) { float* p = (float*)w; w += cnt * 4; return p; };
    auto alloc_i = [&](size_t cnt) { int*   p = (int*)w;   w += cnt * 4; return p; };
    auto alloc_h = [&](size_t cnt) { __half* p = (__half*)w; w += cnt * 2; return p; };

    float*    dinv   = alloc_f(n);
    int*      start  = alloc_i(n);
    unsigned* poff   = (unsigned*)alloc_i(n);
    int*      cnt1   = alloc_i((size_t)NBLK1 * PAD1);
    int*      po1    = alloc_i((size_t)NBLK1 * PAD1);
    int*      totals = alloc_i(512);
    unsigned* ebuf   = (unsigned*)alloc_i(nE);   // 12.8 MB
    int*      col    = alloc_i(nE);              // 12.8 MB
    __half* Pd1 = alloc_h((size_t)n * 16);  // 3.2 MB fp16
    __half* h1d = alloc_h((size_t)n * 16);  // 3.2 MB fp16
    __half* h2d = alloc_h((size_t)n * 32);  // 6.4 MB fp16
    float*  h3  = alloc_f((size_t)n * 64);  // f32 (feeds poolhead)

    const int B = 256;
    auto g = [&](long long t) { return (int)((t + B - 1) / B); };

    // ---- CSR build: two-level radix, zero global atomics
    k_hist1<<<NBLK1, 1024, 0, stream>>>(dst, cnt1, nE, NSB);
    k_scan1<<<NSB, 512, 0, stream>>>(cnt1, po1, totals, NBLK1);
    k_scat1<<<NBLK1, 1024, 0, stream>>>(src, dst, po1, totals, ebuf, nE, NSB);
    k_sort2<<<NSB, 512, 0, stream>>>(ebuf, totals, col, start, dinv, poff, n,
                                     qmagic, NSB);

    // ---- layer 1: Pd1 = dinv*(x@W1) [fp16]; h1d = dinv*relu(dinv*Agg(Pd1)+b1)
    k_mm1<<<(n + 63) / 64, 256, 0, stream>>>((const float4*)x, (const float4*)W1,
                                             dinv, Pd1, n);
    k_aggf16<<<g((long long)n * 4), B, 0, stream>>>((const uint4*)Pd1, start, poff,
                                                    col, dinv, b1, (uint4*)h1d, n);

    // ---- layer 2 (agg + mm2 fused): h2d = dinv*relu((dinv*Agg(h1d))@W2+b2)
    k_aggf16_mm2<<<g((long long)n * 4), B, 0, stream>>>((const uint4*)h1d, start,
                                                        poff, col, dinv, W2, b2,
                                                        (uint4*)h2d, n);

    // ---- layer 3 (agg + mm3 fused): h3 = relu((dinv*Agg(h2d))@W3+b3)
    k_aggf32_mm3<<<(int)(((long long)n * 8 + 511) / 512), 512, 0, stream>>>(
        (const uint4*)h2d, start, poff, col, dinv, W3, b3, h3, n);

    // ---- fused mean-pool + head (no atomics; batch is sorted)
    k_poolhead<<<NG, 256, 0, stream>>>(h3, batch, Wl1, bl1, Wl2, bl2, out, n);
}

// Round 19
// 196.081 us; speedup vs baseline: 1.3958x; 1.0079x over previous
//
#include <hip/hip_runtime.h>
#include <hip/hip_fp16.h>

// GCN forward: 3x GCNConv (symmetric norm, self-loops) + mean-pool + MLP head.
// R19: split-K WITHIN each quartile (front-half/back-half lane groups walking
//      the same quartile sequence) — keeps R18's 2x wave count + halved chains
//      while restoring R17's single-quartile live footprint (FETCH 69->44MB
//      regression traced to R18's cross-quartile split).

constexpr int EPA1 = 8192;   // edges per level-1 block
constexpr int NPSB = 256;    // nodes per super-bucket
constexpr int PAD1 = 400;    // [blk][sb] metadata row stride

// ---- fp16 helpers: uint4 = 8 halves
__device__ __forceinline__ void acc8(float4& A, float4& B, uint4 u) {
    __half2* ph = reinterpret_cast<__half2*>(&u);
    float2 f0 = __half22float2(ph[0]);
    float2 f1 = __half22float2(ph[1]);
    float2 f2 = __half22float2(ph[2]);
    float2 f3 = __half22float2(ph[3]);
    A.x += f0.x; A.y += f0.y; A.z += f1.x; A.w += f1.y;
    B.x += f2.x; B.y += f2.y; B.z += f3.x; B.w += f3.y;
}
__device__ __forceinline__ uint4 pack8(const float* h) {
    __half2 a = __floats2half2_rn(h[0], h[1]);
    __half2 b = __floats2half2_rn(h[2], h[3]);
    __half2 c = __floats2half2_rn(h[4], h[5]);
    __half2 d = __floats2half2_rn(h[6], h[7]);
    uint4 u;
    u.x = *reinterpret_cast<unsigned*>(&a);
    u.y = *reinterpret_cast<unsigned*>(&b);
    u.z = *reinterpret_cast<unsigned*>(&c);
    u.w = *reinterpret_cast<unsigned*>(&d);
    return u;
}

// ---- level 1 histogram: per-block super-bucket counts
__global__ __launch_bounds__(1024) void k_hist1(const int* __restrict__ dst,
        int* __restrict__ cnt1, int nE, int NSB) {
    __shared__ int hist[512];
    int t = threadIdx.x;
    if (t < 512) hist[t] = 0;
    __syncthreads();
    int base = blockIdx.x * EPA1, end = min(base + EPA1, nE);
    for (int e = base + t; e < end; e += 1024)
        atomicAdd(&hist[dst[e] >> 8], 1);  // LDS
    __syncthreads();
    if (t < NSB) cnt1[blockIdx.x * PAD1 + t] = hist[t];
}

// ---- level 1 scan: per-sb exclusive prefix over blocks; emits totals
__global__ __launch_bounds__(512) void k_scan1(const int* __restrict__ cnt1,
        int* __restrict__ po1, int* __restrict__ totals, int NBLK1) {
    __shared__ int sc[512];
    int sb = blockIdx.x, t = threadIdx.x;
    int v = (t < NBLK1) ? cnt1[t * PAD1 + sb] : 0;
    sc[t] = v;
    __syncthreads();
    for (int off = 1; off < 512; off <<= 1) {
        int u = (t >= off) ? sc[t - off] : 0;
        __syncthreads();
        sc[t] += u;
        __syncthreads();
    }
    if (t < NBLK1) po1[t * PAD1 + sb] = sc[t] - v;
    if (t == 511) totals[sb] = sc[511];
}

// ---- level 1 scatter: edges -> super-bucket-major ebuf (packed lnode|src).
__global__ __launch_bounds__(1024) void k_scat1(const int* __restrict__ src,
        const int* __restrict__ dst, const int* __restrict__ po1,
        const int* __restrict__ totals, unsigned* __restrict__ ebuf,
        int nE, int NSB) {
    __shared__ int sc[512], cur[512];
    int t = threadIdx.x, blk = blockIdx.x;
    if (t < 512) sc[t] = (t < NSB) ? totals[t] : 0;
    __syncthreads();
    for (int off = 1; off < 512; off <<= 1) {
        int u = (t >= off && t < 512) ? sc[t - off] : 0;
        __syncthreads();
        if (t < 512) sc[t] += u;
        __syncthreads();
    }
    if (t < NSB) cur[t] = (sc[t] - totals[t]) + po1[blk * PAD1 + t];
    __syncthreads();
    int base = blk * EPA1, end = min(base + EPA1, nE);
    for (int e = base + t; e < end; e += 1024) {
        int s = src[e], d = dst[e];
        int pos = atomicAdd(&cur[d >> 8], 1);  // LDS
        ebuf[pos] = ((unsigned)(d & 255) << 17) | (unsigned)s;
    }
}

// ---- level 2: per-sb contiguous counting sort by (node, src-quartile)
__global__ __launch_bounds__(512) void k_sort2(const unsigned* __restrict__ ebuf,
        const int* __restrict__ totals, int* __restrict__ col,
        int* __restrict__ start, float* __restrict__ dinv,
        unsigned* __restrict__ poff, int n, unsigned qmagic, int NSB) {
    __shared__ int sc[512];
    __shared__ int hist4[1024], cur4[1024], excl[256];
    int b = blockIdx.x, t = threadIdx.x;
    sc[t] = (t < NSB) ? totals[t] : 0;
    __syncthreads();
    for (int off = 1; off < 512; off <<= 1) {
        int u = (t >= off) ? sc[t - off] : 0;
        __syncthreads();
        sc[t] += u;
        __syncthreads();
    }
    int eend = sc[b], ebase = eend - totals[b];
    hist4[t] = 0; hist4[t + 512] = 0;
    __syncthreads();
    for (int e = ebase + t; e < eend; e += 512) {
        unsigned u = ebuf[e];
        unsigned s = u & 0x1FFFFu;
        atomicAdd(&hist4[(u >> 17) * 4 + __umulhi(s, qmagic)], 1);  // LDS
    }
    __syncthreads();
    int c0 = 0, c1 = 0, c2 = 0, c3 = 0, v = 0;
    if (t < 256) {
        c0 = hist4[t * 4];     c1 = hist4[t * 4 + 1];
        c2 = hist4[t * 4 + 2]; c3 = hist4[t * 4 + 3];
        v = c0 + c1 + c2 + c3;
        excl[t] = v;
    }
    __syncthreads();
    for (int off = 1; off < 256; off <<= 1) {
        int u = (t >= off && t < 256) ? excl[t - off] : 0;
        __syncthreads();
        if (t < 256) excl[t] += u;
        __syncthreads();
    }
    if (t < 256) {
        int sbase = ebase + excl[t] - v;
        cur4[t * 4]     = sbase;
        cur4[t * 4 + 1] = sbase + c0;
        cur4[t * 4 + 2] = sbase + c0 + c1;
        cur4[t * 4 + 3] = sbase + c0 + c1 + c2;
        int node = (b << 8) + t;
        if (node < n) {
            start[node] = sbase;
            dinv[node] = rsqrtf((float)(v + 1));
            poff[node] = (unsigned)c0 | ((unsigned)c1 << 8) |
                         ((unsigned)c2 << 16) | ((unsigned)c3 << 24);
        }
    }
    __syncthreads();
    for (int e = ebase + t; e < eend; e += 512) {
        unsigned u = ebuf[e];
        unsigned s = u & 0x1FFFFu;
        int pos = atomicAdd(&cur4[(u >> 17) * 4 + __umulhi(s, qmagic)], 1);  // LDS
        col[pos] = (int)s;
    }
}

// ---- split gather: both halves (h=0 front, h=1 back) walk quartiles 0..3 in
//      lockstep, so the live src footprint stays one quartile wide.
template <int U4PR>
__device__ __forceinline__ void agg_gather_split(const uint4* __restrict__ T,
        const int* __restrict__ col, int base, unsigned pk, int h, int q,
        float4& A, float4& B) {
    #pragma unroll
    for (int p = 0; p < 4; ++p) {
        int len = (int)((pk >> (8 * p)) & 255u);
        int lenH = (len + 1) >> 1;          // front-half size
        int b0 = base + (h ? lenH : 0);
        int cnt = h ? (len - lenH) : lenH;
        int k = 0;
        for (; k + 4 <= cnt; k += 4) {
            uint4 u0 = T[(size_t)col[b0 + k]     * U4PR + q];
            uint4 u1 = T[(size_t)col[b0 + k + 1] * U4PR + q];
            uint4 u2 = T[(size_t)col[b0 + k + 2] * U4PR + q];
            uint4 u3 = T[(size_t)col[b0 + k + 3] * U4PR + q];
            acc8(A, B, u0); acc8(A, B, u1); acc8(A, B, u2); acc8(A, B, u3);
        }
        for (; k < cnt; ++k)
            acc8(A, B, T[(size_t)col[b0 + k] * U4PR + q]);
        base += len;
    }
}
__device__ __forceinline__ void combine(float4& A, float4& B, int xorMask) {
    A.x += __shfl_xor(A.x, xorMask); A.y += __shfl_xor(A.y, xorMask);
    A.z += __shfl_xor(A.z, xorMask); A.w += __shfl_xor(A.w, xorMask);
    B.x += __shfl_xor(B.x, xorMask); B.y += __shfl_xor(B.y, xorMask);
    B.z += __shfl_xor(B.z, xorMask); B.w += __shfl_xor(B.w, xorMask);
}

// ---- layer-1 agg (F=16, 4 lanes/node: q=sub&1, h=sub>>1)
__global__ void k_aggf16(const uint4* __restrict__ T, const int* __restrict__ start,
        const unsigned* __restrict__ poff, const int* __restrict__ col,
        const float* __restrict__ dinv, const float* __restrict__ bias,
        uint4* __restrict__ out, int n) {
    int idx = blockIdx.x * blockDim.x + threadIdx.x;
    int i = idx >> 2, sub = idx & 3;
    if (i >= n) return;
    int q = sub & 1, h = sub >> 1;
    unsigned pk = poff[i];
    float4 A = make_float4(0.f, 0.f, 0.f, 0.f);
    float4 B = make_float4(0.f, 0.f, 0.f, 0.f);
    if (h == 0) acc8(A, B, T[(size_t)i * 2 + q]);  // self term once
    agg_gather_split<2>(T, col, start[i], pk, h, q, A, B);
    combine(A, B, 2);
    if (h) return;
    float d = dinv[i];
    float4 bA = ((const float4*)bias)[q * 2];
    float4 bB = ((const float4*)bias)[q * 2 + 1];
    float ho[8];
    ho[0] = d * fmaxf(d * A.x + bA.x, 0.0f);
    ho[1] = d * fmaxf(d * A.y + bA.y, 0.0f);
    ho[2] = d * fmaxf(d * A.z + bA.z, 0.0f);
    ho[3] = d * fmaxf(d * A.w + bA.w, 0.0f);
    ho[4] = d * fmaxf(d * B.x + bB.x, 0.0f);
    ho[5] = d * fmaxf(d * B.y + bB.y, 0.0f);
    ho[6] = d * fmaxf(d * B.z + bB.z, 0.0f);
    ho[7] = d * fmaxf(d * B.w + bB.w, 0.0f);
    out[(size_t)i * 2 + q] = pack8(ho);
}

// ---- layer-2 agg + mm2 (F=16, 4 lanes/node): all 4 lanes run the epilogue.
__global__ __launch_bounds__(256) void k_aggf16_mm2(const uint4* __restrict__ T,
        const int* __restrict__ start, const unsigned* __restrict__ poff,
        const int* __restrict__ col, const float* __restrict__ dinv,
        const float* __restrict__ W2, const float* __restrict__ b2,
        uint4* __restrict__ out, int n) {
    __shared__ float sW[16 * 32];
    __shared__ float sB[32];
    int t = threadIdx.x;
    for (int j = t; j < 512; j += 256) sW[j] = W2[j];
    if (t < 32) sB[t] = b2[t];
    __syncthreads();
    int idx = blockIdx.x * blockDim.x + t;
    int i = idx >> 2, sub = idx & 3;
    if (i >= n) return;
    int q = sub & 1, h = sub >> 1;
    unsigned pk = poff[i];
    float4 A = make_float4(0.f, 0.f, 0.f, 0.f);
    float4 B = make_float4(0.f, 0.f, 0.f, 0.f);
    if (h == 0) acc8(A, B, T[(size_t)i * 2 + q]);
    agg_gather_split<2>(T, col, start[i], pk, h, q, A, B);
    combine(A, B, 2);
    float d = dinv[i];
    float a[8] = {d * A.x, d * A.y, d * A.z, d * A.w,
                  d * B.x, d * B.y, d * B.z, d * B.w};  // a1 frag for uint4 q
    int lane = t & 63;
    int gbase = lane & ~3;  // 4-lane group
    float hacc[8];
    #pragma unroll
    for (int o = 0; o < 8; ++o) hacc[o] = sB[sub * 8 + o];
    #pragma unroll
    for (int j = 0; j < 2; ++j) {
        #pragma unroll
        for (int kk = 0; kk < 8; ++kk) {
            float ak = __shfl(a[kk], gbase + j);  // lane sub=j holds frag q=j
            const float* w0 = &sW[(j * 8 + kk) * 32 + sub * 8];
            #pragma unroll
            for (int o = 0; o < 8; ++o) hacc[o] += ak * w0[o];
        }
    }
    float ho[8];
    #pragma unroll
    for (int o = 0; o < 8; ++o) ho[o] = d * fmaxf(hacc[o], 0.0f);
    out[(size_t)i * 4 + sub] = pack8(ho);
}

// ---- layer-3 agg + mm3 (F=32, 8 lanes/node: q=sub&3, h=sub>>2).
__global__ __launch_bounds__(512) void k_aggf32_mm3(const uint4* __restrict__ T,
        const int* __restrict__ start, const unsigned* __restrict__ poff,
        const int* __restrict__ col, const float* __restrict__ dinv,
        const float* __restrict__ W3, const float* __restrict__ b3,
        float* __restrict__ out, int n) {
    __shared__ float sW[32 * 64];
    __shared__ float sB[64];
    int t = threadIdx.x;
    for (int j = t; j < 2048; j += 512) sW[j] = W3[j];
    if (t < 64) sB[t] = b3[t];
    __syncthreads();
    int idx = blockIdx.x * blockDim.x + t;
    int i = idx >> 3, sub = idx & 7;
    if (i >= n) return;
    int q = sub & 3, h = sub >> 2;
    unsigned pk = poff[i];
    float4 A = make_float4(0.f, 0.f, 0.f, 0.f);
    float4 B = make_float4(0.f, 0.f, 0.f, 0.f);
    if (h == 0) acc8(A, B, T[(size_t)i * 4 + q]);
    agg_gather_split<4>(T, col, start[i], pk, h, q, A, B);
    combine(A, B, 4);
    float d = dinv[i];
    float a[8] = {d * A.x, d * A.y, d * A.z, d * A.w,
                  d * B.x, d * B.y, d * B.z, d * B.w};  // a2 frag for uint4 q
    int lane = t & 63;
    int gbase = lane & ~7;  // 8-lane group
    float hacc[8];
    #pragma unroll
    for (int o = 0; o < 8; ++o) hacc[o] = sB[sub * 8 + o];
    #pragma unroll
    for (int j = 0; j < 4; ++j) {
        #pragma unroll
        for (int kk = 0; kk < 8; ++kk) {
            float ak = __shfl(a[kk], gbase + j);  // lane sub=j holds frag q=j
            const float* w0 = &sW[(j * 8 + kk) * 64 + sub * 8];
            #pragma unroll
            for (int o = 0; o < 8; ++o) hacc[o] += ak * w0[o];
        }
    }
    float4 o0, o1;
    o0.x = fmaxf(hacc[0], 0.f); o0.y = fmaxf(hacc[1], 0.f);
    o0.z = fmaxf(hacc[2], 0.f); o0.w = fmaxf(hacc[3], 0.f);
    o1.x = fmaxf(hacc[4], 0.f); o1.y = fmaxf(hacc[5], 0.f);
    o1.z = fmaxf(hacc[6], 0.f); o1.w = fmaxf(hacc[7], 0.f);
    float4* O4 = (float4*)out;
    size_t rb = (size_t)i * 16 + sub * 2;
    O4[rb] = o0; O4[rb + 1] = o1;
}

// ---- mm1: Pd1 (fp16) = dinv * (x @ W1), K=128 F=16. LDS-tiled.
__global__ __launch_bounds__(256) void k_mm1(const float4* __restrict__ X4,
        const float4* __restrict__ W4, const float* __restrict__ dinv,
        __half* __restrict__ out, int n) {
    __shared__ float4 xs[64 * 32];
    __shared__ float4 ws[512];
    int t = threadIdx.x;
    int nb = blockIdx.x * 64;
    ws[t] = W4[t]; ws[t + 256] = W4[t + 256];
    int lim = min(64, n - nb);
    #pragma unroll
    for (int it = 0; it < 8; ++it) {
        int idx = it * 256 + t;
        if ((idx >> 5) < lim) xs[idx] = X4[(size_t)nb * 32 + idx];
    }
    __syncthreads();
    int lane = t & 63, wv = t >> 6;
    int f = lane & 15, kc = lane >> 4;
    float wcol[32];
    #pragma unroll
    for (int kk = 0; kk < 32; ++kk)
        wcol[kk] = ((const float*)ws)[(kc * 32 + kk) * 16 + f];
    for (int ln = wv * 16; ln < wv * 16 + 16; ++ln) {
        if (ln >= lim) break;
        int i = nb + ln;
        float acc = 0.0f;
        #pragma unroll
        for (int j = 0; j < 8; ++j) {
            float4 hv = xs[ln * 32 + kc * 8 + j];
            acc += hv.x * wcol[4 * j]     + hv.y * wcol[4 * j + 1]
                 + hv.z * wcol[4 * j + 2] + hv.w * wcol[4 * j + 3];
        }
        acc += __shfl_xor(acc, 16);
        acc += __shfl_xor(acc, 32);
        if (kc == 0) out[(size_t)i * 16 + f] = __float2half_rn(acc * dinv[i]);
    }
}

// ---- fused mean-pool + MLP head: 256 threads per graph (4-way row parallel)
__global__ __launch_bounds__(256) void k_poolhead(const float* __restrict__ h3,
        const int* __restrict__ batch, const float* __restrict__ Wl1,
        const float* __restrict__ bl1, const float* __restrict__ Wl2,
        const float* __restrict__ bl2, float* __restrict__ out, int n) {
    int g = blockIdx.x, t = threadIdx.x;
    int f = t & 63, r = t >> 6;
    __shared__ int sb[2];
    __shared__ float part[4][64];
    __shared__ float mean[64], hid[64];
    if (t < 2) {
        int target = g + t;
        int lo = 0, hi = n;
        while (lo < hi) {
            int mid = (lo + hi) >> 1;
            if (batch[mid] < target) lo = mid + 1; else hi = mid;
        }
        sb[t] = lo;
    }
    __syncthreads();
    int s = sb[0], e = sb[1];
    float acc = 0.0f;
    for (int i = s + r; i < e; i += 4) acc += h3[(size_t)i * 64 + f];
    part[r][f] = acc;
    __syncthreads();
    if (t < 64) {
        float c = fmaxf((float)(e - s), 1.0f);
        mean[t] = (part[0][t] + part[1][t] + part[2][t] + part[3][t]) / c;
    }
    __syncthreads();
    if (t < 64) {
        float a = bl1[t];
        #pragma unroll 8
        for (int k = 0; k < 64; ++k) a += mean[k] * Wl1[k * 64 + t];
        hid[t] = fmaxf(a, 0.0f);
    }
    __syncthreads();
    if (t < 2) {
        float o = bl2[t];
        #pragma unroll 8
        for (int k = 0; k < 64; ++k) o += hid[k] * Wl2[k * 2 + t];
        out[g * 2 + t] = o;
    }
}

extern "C" void kernel_launch(void* const* d_in, const int* in_sizes, int n_in,
                              void* d_out, int out_size, void* d_ws, size_t ws_size,
                              hipStream_t stream) {
    const float* x    = (const float*)d_in[0];
    const int*   ei   = (const int*)d_in[1];
    const int*   batch= (const int*)d_in[2];
    const float* W1   = (const float*)d_in[3];
    const float* b1   = (const float*)d_in[4];
    const float* W2   = (const float*)d_in[5];
    const float* b2   = (const float*)d_in[6];
    const float* W3   = (const float*)d_in[7];
    const float* b3   = (const float*)d_in[8];
    const float* Wl1  = (const float*)d_in[9];
    const float* bl1  = (const float*)d_in[10];
    const float* Wl2  = (const float*)d_in[11];
    const float* bl2  = (const float*)d_in[12];
    float* out = (float*)d_out;

    const int n  = in_sizes[2];      // 100000
    const int nE = in_sizes[1] / 2;  // 3200000
    const int* src = ei;
    const int* dst = ei + nE;

    const int NSB   = (n + NPSB - 1) / NPSB;   // 391 super-buckets (256 nodes)
    const int NBLK1 = (nE + EPA1 - 1) / EPA1;  // 391 level-1 blocks
    const int NG    = 1024;
    const int qsz   = (n + 3) / 4;             // src-quartile size
    const unsigned qmagic = (unsigned)((0x100000000ULL + qsz - 1) / qsz);

    char* w = (char*)d_ws;
    auto alloc_f = [&](size_t cnt) { float* p = (float*)w; w += cnt * 4; return p; };
    auto alloc_i = [&](size_t cnt) { int*   p = (int*)w;   w += cnt * 4; return p; };
    auto alloc_h = [&](size_t cnt) { __half* p = (__half*)w; w += cnt * 2; return p; };

    float*    dinv   = alloc_f(n);
    int*      start  = alloc_i(n);
    unsigned* poff   = (unsigned*)alloc_i(n);
    int*      cnt1   = alloc_i((size_t)NBLK1 * PAD1);
    int*      po1    = alloc_i((size_t)NBLK1 * PAD1);
    int*      totals = alloc_i(512);
    unsigned* ebuf   = (unsigned*)alloc_i(nE);   // 12.8 MB
    int*      col    = alloc_i(nE);              // 12.8 MB
    __half* Pd1 = alloc_h((size_t)n * 16);  // 3.2 MB fp16
    __half* h1d = alloc_h((size_t)n * 16);  // 3.2 MB fp16
    __half* h2d = alloc_h((size_t)n * 32);  // 6.4 MB fp16
    float*  h3  = alloc_f((size_t)n * 64);  // f32 (feeds poolhead)

    const int B = 256;
    auto g = [&](long long t) { return (int)((t + B - 1) / B); };

    // ---- CSR build: two-level radix, zero global atomics
    k_hist1<<<NBLK1, 1024, 0, stream>>>(dst, cnt1, nE, NSB);
    k_scan1<<<NSB, 512, 0, stream>>>(cnt1, po1, totals, NBLK1);
    k_scat1<<<NBLK1, 1024, 0, stream>>>(src, dst, po1, totals, ebuf, nE, NSB);
    k_sort2<<<NSB, 512, 0, stream>>>(ebuf, totals, col, start, dinv, poff, n,
                                     qmagic, NSB);

    // ---- layer 1: Pd1 = dinv*(x@W1) [fp16]; h1d = dinv*relu(dinv*Agg(Pd1)+b1)
    k_mm1<<<(n + 63) / 64, 256, 0, stream>>>((const float4*)x, (const float4*)W1,
                                             dinv, Pd1, n);
    k_aggf16<<<g((long long)n * 4), B, 0, stream>>>((const uint4*)Pd1, start, poff,
                                                    col, dinv, b1, (uint4*)h1d, n);

    // ---- layer 2 (agg + mm2 fused): h2d = dinv*relu((dinv*Agg(h1d))@W2+b2)
    k_aggf16_mm2<<<g((long long)n * 4), B, 0, stream>>>((const uint4*)h1d, start,
                                                        poff, col, dinv, W2, b2,
                                                        (uint4*)h2d, n);

    // ---- layer 3 (agg + mm3 fused): h3 = relu((dinv*Agg(h2d))@W3+b3)
    k_aggf32_mm3<<<(int)(((long long)n * 8 + 511) / 512), 512, 0, stream>>>(
        (const uint4*)h2d, start, poff, col, dinv, W3, b3, h3, n);

    // ---- fused mean-pool + head (no atomics; batch is sorted)
    k_poolhead<<<NG, 256, 0, stream>>>(h3, batch, Wl1, bl1, Wl2, bl2, out, n);
}

// Round 20
// 189.140 us; speedup vs baseline: 1.4470x; 1.0367x over previous
//
#include <hip/hip_runtime.h>
#include <hip/hip_fp16.h>

// GCN forward: 3x GCNConv (symmetric norm, self-loops) + mean-pool + MLP head.
// R20: R19 + fp16 h3 (halves aggf32_mm3 write + poolhead read) and 32-way
//      row-parallel poolhead. Gather confirmed at its floor (R17/18/19 all
//      48-50us across 44-69MB FETCH, 42-56% occ).

constexpr int EPA1 = 8192;   // edges per level-1 block
constexpr int NPSB = 256;    // nodes per super-bucket
constexpr int PAD1 = 400;    // [blk][sb] metadata row stride

// ---- fp16 helpers: uint4 = 8 halves
__device__ __forceinline__ void acc8(float4& A, float4& B, uint4 u) {
    __half2* ph = reinterpret_cast<__half2*>(&u);
    float2 f0 = __half22float2(ph[0]);
    float2 f1 = __half22float2(ph[1]);
    float2 f2 = __half22float2(ph[2]);
    float2 f3 = __half22float2(ph[3]);
    A.x += f0.x; A.y += f0.y; A.z += f1.x; A.w += f1.y;
    B.x += f2.x; B.y += f2.y; B.z += f3.x; B.w += f3.y;
}
__device__ __forceinline__ uint4 pack8(const float* h) {
    __half2 a = __floats2half2_rn(h[0], h[1]);
    __half2 b = __floats2half2_rn(h[2], h[3]);
    __half2 c = __floats2half2_rn(h[4], h[5]);
    __half2 d = __floats2half2_rn(h[6], h[7]);
    uint4 u;
    u.x = *reinterpret_cast<unsigned*>(&a);
    u.y = *reinterpret_cast<unsigned*>(&b);
    u.z = *reinterpret_cast<unsigned*>(&c);
    u.w = *reinterpret_cast<unsigned*>(&d);
    return u;
}

// ---- level 1 histogram: per-block super-bucket counts
__global__ __launch_bounds__(1024) void k_hist1(const int* __restrict__ dst,
        int* __restrict__ cnt1, int nE, int NSB) {
    __shared__ int hist[512];
    int t = threadIdx.x;
    if (t < 512) hist[t] = 0;
    __syncthreads();
    int base = blockIdx.x * EPA1, end = min(base + EPA1, nE);
    for (int e = base + t; e < end; e += 1024)
        atomicAdd(&hist[dst[e] >> 8], 1);  // LDS
    __syncthreads();
    if (t < NSB) cnt1[blockIdx.x * PAD1 + t] = hist[t];
}

// ---- level 1 scan: per-sb exclusive prefix over blocks; emits totals
__global__ __launch_bounds__(512) void k_scan1(const int* __restrict__ cnt1,
        int* __restrict__ po1, int* __restrict__ totals, int NBLK1) {
    __shared__ int sc[512];
    int sb = blockIdx.x, t = threadIdx.x;
    int v = (t < NBLK1) ? cnt1[t * PAD1 + sb] : 0;
    sc[t] = v;
    __syncthreads();
    for (int off = 1; off < 512; off <<= 1) {
        int u = (t >= off) ? sc[t - off] : 0;
        __syncthreads();
        sc[t] += u;
        __syncthreads();
    }
    if (t < NBLK1) po1[t * PAD1 + sb] = sc[t] - v;
    if (t == 511) totals[sb] = sc[511];
}

// ---- level 1 scatter: edges -> super-bucket-major ebuf (packed lnode|src).
__global__ __launch_bounds__(1024) void k_scat1(const int* __restrict__ src,
        const int* __restrict__ dst, const int* __restrict__ po1,
        const int* __restrict__ totals, unsigned* __restrict__ ebuf,
        int nE, int NSB) {
    __shared__ int sc[512], cur[512];
    int t = threadIdx.x, blk = blockIdx.x;
    if (t < 512) sc[t] = (t < NSB) ? totals[t] : 0;
    __syncthreads();
    for (int off = 1; off < 512; off <<= 1) {
        int u = (t >= off && t < 512) ? sc[t - off] : 0;
        __syncthreads();
        if (t < 512) sc[t] += u;
        __syncthreads();
    }
    if (t < NSB) cur[t] = (sc[t] - totals[t]) + po1[blk * PAD1 + t];
    __syncthreads();
    int base = blk * EPA1, end = min(base + EPA1, nE);
    for (int e = base + t; e < end; e += 1024) {
        int s = src[e], d = dst[e];
        int pos = atomicAdd(&cur[d >> 8], 1);  // LDS
        ebuf[pos] = ((unsigned)(d & 255) << 17) | (unsigned)s;
    }
}

// ---- level 2: per-sb contiguous counting sort by (node, src-quartile)
__global__ __launch_bounds__(512) void k_sort2(const unsigned* __restrict__ ebuf,
        const int* __restrict__ totals, int* __restrict__ col,
        int* __restrict__ start, float* __restrict__ dinv,
        unsigned* __restrict__ poff, int n, unsigned qmagic, int NSB) {
    __shared__ int sc[512];
    __shared__ int hist4[1024], cur4[1024], excl[256];
    int b = blockIdx.x, t = threadIdx.x;
    sc[t] = (t < NSB) ? totals[t] : 0;
    __syncthreads();
    for (int off = 1; off < 512; off <<= 1) {
        int u = (t >= off) ? sc[t - off] : 0;
        __syncthreads();
        sc[t] += u;
        __syncthreads();
    }
    int eend = sc[b], ebase = eend - totals[b];
    hist4[t] = 0; hist4[t + 512] = 0;
    __syncthreads();
    for (int e = ebase + t; e < eend; e += 512) {
        unsigned u = ebuf[e];
        unsigned s = u & 0x1FFFFu;
        atomicAdd(&hist4[(u >> 17) * 4 + __umulhi(s, qmagic)], 1);  // LDS
    }
    __syncthreads();
    int c0 = 0, c1 = 0, c2 = 0, c3 = 0, v = 0;
    if (t < 256) {
        c0 = hist4[t * 4];     c1 = hist4[t * 4 + 1];
        c2 = hist4[t * 4 + 2]; c3 = hist4[t * 4 + 3];
        v = c0 + c1 + c2 + c3;
        excl[t] = v;
    }
    __syncthreads();
    for (int off = 1; off < 256; off <<= 1) {
        int u = (t >= off && t < 256) ? excl[t - off] : 0;
        __syncthreads();
        if (t < 256) excl[t] += u;
        __syncthreads();
    }
    if (t < 256) {
        int sbase = ebase + excl[t] - v;
        cur4[t * 4]     = sbase;
        cur4[t * 4 + 1] = sbase + c0;
        cur4[t * 4 + 2] = sbase + c0 + c1;
        cur4[t * 4 + 3] = sbase + c0 + c1 + c2;
        int node = (b << 8) + t;
        if (node < n) {
            start[node] = sbase;
            dinv[node] = rsqrtf((float)(v + 1));
            poff[node] = (unsigned)c0 | ((unsigned)c1 << 8) |
                         ((unsigned)c2 << 16) | ((unsigned)c3 << 24);
        }
    }
    __syncthreads();
    for (int e = ebase + t; e < eend; e += 512) {
        unsigned u = ebuf[e];
        unsigned s = u & 0x1FFFFu;
        int pos = atomicAdd(&cur4[(u >> 17) * 4 + __umulhi(s, qmagic)], 1);  // LDS
        col[pos] = (int)s;
    }
}

// ---- split gather: both halves (h=0 front, h=1 back) walk quartiles 0..3 in
//      lockstep, so the live src footprint stays one quartile wide.
template <int U4PR>
__device__ __forceinline__ void agg_gather_split(const uint4* __restrict__ T,
        const int* __restrict__ col, int base, unsigned pk, int h, int q,
        float4& A, float4& B) {
    #pragma unroll
    for (int p = 0; p < 4; ++p) {
        int len = (int)((pk >> (8 * p)) & 255u);
        int lenH = (len + 1) >> 1;          // front-half size
        int b0 = base + (h ? lenH : 0);
        int cnt = h ? (len - lenH) : lenH;
        int k = 0;
        for (; k + 4 <= cnt; k += 4) {
            uint4 u0 = T[(size_t)col[b0 + k]     * U4PR + q];
            uint4 u1 = T[(size_t)col[b0 + k + 1] * U4PR + q];
            uint4 u2 = T[(size_t)col[b0 + k + 2] * U4PR + q];
            uint4 u3 = T[(size_t)col[b0 + k + 3] * U4PR + q];
            acc8(A, B, u0); acc8(A, B, u1); acc8(A, B, u2); acc8(A, B, u3);
        }
        for (; k < cnt; ++k)
            acc8(A, B, T[(size_t)col[b0 + k] * U4PR + q]);
        base += len;
    }
}
__device__ __forceinline__ void combine(float4& A, float4& B, int xorMask) {
    A.x += __shfl_xor(A.x, xorMask); A.y += __shfl_xor(A.y, xorMask);
    A.z += __shfl_xor(A.z, xorMask); A.w += __shfl_xor(A.w, xorMask);
    B.x += __shfl_xor(B.x, xorMask); B.y += __shfl_xor(B.y, xorMask);
    B.z += __shfl_xor(B.z, xorMask); B.w += __shfl_xor(B.w, xorMask);
}

// ---- layer-1 agg (F=16, 4 lanes/node: q=sub&1, h=sub>>1)
__global__ void k_aggf16(const uint4* __restrict__ T, const int* __restrict__ start,
        const unsigned* __restrict__ poff, const int* __restrict__ col,
        const float* __restrict__ dinv, const float* __restrict__ bias,
        uint4* __restrict__ out, int n) {
    int idx = blockIdx.x * blockDim.x + threadIdx.x;
    int i = idx >> 2, sub = idx & 3;
    if (i >= n) return;
    int q = sub & 1, h = sub >> 1;
    unsigned pk = poff[i];
    float4 A = make_float4(0.f, 0.f, 0.f, 0.f);
    float4 B = make_float4(0.f, 0.f, 0.f, 0.f);
    if (h == 0) acc8(A, B, T[(size_t)i * 2 + q]);  // self term once
    agg_gather_split<2>(T, col, start[i], pk, h, q, A, B);
    combine(A, B, 2);
    if (h) return;
    float d = dinv[i];
    float4 bA = ((const float4*)bias)[q * 2];
    float4 bB = ((const float4*)bias)[q * 2 + 1];
    float ho[8];
    ho[0] = d * fmaxf(d * A.x + bA.x, 0.0f);
    ho[1] = d * fmaxf(d * A.y + bA.y, 0.0f);
    ho[2] = d * fmaxf(d * A.z + bA.z, 0.0f);
    ho[3] = d * fmaxf(d * A.w + bA.w, 0.0f);
    ho[4] = d * fmaxf(d * B.x + bB.x, 0.0f);
    ho[5] = d * fmaxf(d * B.y + bB.y, 0.0f);
    ho[6] = d * fmaxf(d * B.z + bB.z, 0.0f);
    ho[7] = d * fmaxf(d * B.w + bB.w, 0.0f);
    out[(size_t)i * 2 + q] = pack8(ho);
}

// ---- layer-2 agg + mm2 (F=16, 4 lanes/node): all 4 lanes run the epilogue.
__global__ __launch_bounds__(256) void k_aggf16_mm2(const uint4* __restrict__ T,
        const int* __restrict__ start, const unsigned* __restrict__ poff,
        const int* __restrict__ col, const float* __restrict__ dinv,
        const float* __restrict__ W2, const float* __restrict__ b2,
        uint4* __restrict__ out, int n) {
    __shared__ float sW[16 * 32];
    __shared__ float sB[32];
    int t = threadIdx.x;
    for (int j = t; j < 512; j += 256) sW[j] = W2[j];
    if (t < 32) sB[t] = b2[t];
    __syncthreads();
    int idx = blockIdx.x * blockDim.x + t;
    int i = idx >> 2, sub = idx & 3;
    if (i >= n) return;
    int q = sub & 1, h = sub >> 1;
    unsigned pk = poff[i];
    float4 A = make_float4(0.f, 0.f, 0.f, 0.f);
    float4 B = make_float4(0.f, 0.f, 0.f, 0.f);
    if (h == 0) acc8(A, B, T[(size_t)i * 2 + q]);
    agg_gather_split<2>(T, col, start[i], pk, h, q, A, B);
    combine(A, B, 2);
    float d = dinv[i];
    float a[8] = {d * A.x, d * A.y, d * A.z, d * A.w,
                  d * B.x, d * B.y, d * B.z, d * B.w};  // a1 frag for uint4 q
    int lane = t & 63;
    int gbase = lane & ~3;  // 4-lane group
    float hacc[8];
    #pragma unroll
    for (int o = 0; o < 8; ++o) hacc[o] = sB[sub * 8 + o];
    #pragma unroll
    for (int j = 0; j < 2; ++j) {
        #pragma unroll
        for (int kk = 0; kk < 8; ++kk) {
            float ak = __shfl(a[kk], gbase + j);  // lane sub=j holds frag q=j
            const float* w0 = &sW[(j * 8 + kk) * 32 + sub * 8];
            #pragma unroll
            for (int o = 0; o < 8; ++o) hacc[o] += ak * w0[o];
        }
    }
    float ho[8];
    #pragma unroll
    for (int o = 0; o < 8; ++o) ho[o] = d * fmaxf(hacc[o], 0.0f);
    out[(size_t)i * 4 + sub] = pack8(ho);
}

// ---- layer-3 agg + mm3 (F=32, 8 lanes/node): h3 written fp16.
__global__ __launch_bounds__(512) void k_aggf32_mm3(const uint4* __restrict__ T,
        const int* __restrict__ start, const unsigned* __restrict__ poff,
        const int* __restrict__ col, const float* __restrict__ dinv,
        const float* __restrict__ W3, const float* __restrict__ b3,
        uint4* __restrict__ out, int n) {
    __shared__ float sW[32 * 64];
    __shared__ float sB[64];
    int t = threadIdx.x;
    for (int j = t; j < 2048; j += 512) sW[j] = W3[j];
    if (t < 64) sB[t] = b3[t];
    __syncthreads();
    int idx = blockIdx.x * blockDim.x + t;
    int i = idx >> 3, sub = idx & 7;
    if (i >= n) return;
    int q = sub & 3, h = sub >> 2;
    unsigned pk = poff[i];
    float4 A = make_float4(0.f, 0.f, 0.f, 0.f);
    float4 B = make_float4(0.f, 0.f, 0.f, 0.f);
    if (h == 0) acc8(A, B, T[(size_t)i * 4 + q]);
    agg_gather_split<4>(T, col, start[i], pk, h, q, A, B);
    combine(A, B, 4);
    float d = dinv[i];
    float a[8] = {d * A.x, d * A.y, d * A.z, d * A.w,
                  d * B.x, d * B.y, d * B.z, d * B.w};  // a2 frag for uint4 q
    int lane = t & 63;
    int gbase = lane & ~7;  // 8-lane group
    float hacc[8];
    #pragma unroll
    for (int o = 0; o < 8; ++o) hacc[o] = sB[sub * 8 + o];
    #pragma unroll
    for (int j = 0; j < 4; ++j) {
        #pragma unroll
        for (int kk = 0; kk < 8; ++kk) {
            float ak = __shfl(a[kk], gbase + j);  // lane sub=j holds frag q=j
            const float* w0 = &sW[(j * 8 + kk) * 64 + sub * 8];
            #pragma unroll
            for (int o = 0; o < 8; ++o) hacc[o] += ak * w0[o];
        }
    }
    float ho[8];
    #pragma unroll
    for (int o = 0; o < 8; ++o) ho[o] = fmaxf(hacc[o], 0.0f);
    out[(size_t)i * 8 + sub] = pack8(ho);
}

// ---- mm1: Pd1 (fp16) = dinv * (x @ W1), K=128 F=16. LDS-tiled.
__global__ __launch_bounds__(256) void k_mm1(const float4* __restrict__ X4,
        const float4* __restrict__ W4, const float* __restrict__ dinv,
        __half* __restrict__ out, int n) {
    __shared__ float4 xs[64 * 32];
    __shared__ float4 ws[512];
    int t = threadIdx.x;
    int nb = blockIdx.x * 64;
    ws[t] = W4[t]; ws[t + 256] = W4[t + 256];
    int lim = min(64, n - nb);
    #pragma unroll
    for (int it = 0; it < 8; ++it) {
        int idx = it * 256 + t;
        if ((idx >> 5) < lim) xs[idx] = X4[(size_t)nb * 32 + idx];
    }
    __syncthreads();
    int lane = t & 63, wv = t >> 6;
    int f = lane & 15, kc = lane >> 4;
    float wcol[32];
    #pragma unroll
    for (int kk = 0; kk < 32; ++kk)
        wcol[kk] = ((const float*)ws)[(kc * 32 + kk) * 16 + f];
    for (int ln = wv * 16; ln < wv * 16 + 16; ++ln) {
        if (ln >= lim) break;
        int i = nb + ln;
        float acc = 0.0f;
        #pragma unroll
        for (int j = 0; j < 8; ++j) {
            float4 hv = xs[ln * 32 + kc * 8 + j];
            acc += hv.x * wcol[4 * j]     + hv.y * wcol[4 * j + 1]
                 + hv.z * wcol[4 * j + 2] + hv.w * wcol[4 * j + 3];
        }
        acc += __shfl_xor(acc, 16);
        acc += __shfl_xor(acc, 32);
        if (kc == 0) out[(size_t)i * 16 + f] = __float2half_rn(acc * dinv[i]);
    }
}

// ---- fused mean-pool + MLP head: 256 thr = 32 rows x 8 uint4-slots; fp16 h3.
__global__ __launch_bounds__(256) void k_poolhead(const uint4* __restrict__ H,
        const int* __restrict__ batch, const float* __restrict__ Wl1,
        const float* __restrict__ bl1, const float* __restrict__ Wl2,
        const float* __restrict__ bl2, float* __restrict__ out, int n) {
    int g = blockIdx.x, t = threadIdx.x;
    int r = t >> 3, slot = t & 7;  // 32 rows x 8 slots
    __shared__ int sb[2];
    __shared__ float part[32][64];  // 8KB
    __shared__ float mean[64], hid[64];
    if (t < 2) {
        int target = g + t;
        int lo = 0, hi = n;
        while (lo < hi) {
            int mid = (lo + hi) >> 1;
            if (batch[mid] < target) lo = mid + 1; else hi = mid;
        }
        sb[t] = lo;
    }
    __syncthreads();
    int s = sb[0], e = sb[1];
    float4 A = make_float4(0.f, 0.f, 0.f, 0.f);
    float4 B = make_float4(0.f, 0.f, 0.f, 0.f);
    for (int i = s + r; i < e; i += 32)
        acc8(A, B, H[(size_t)i * 8 + slot]);
    part[r][slot * 8]     = A.x; part[r][slot * 8 + 1] = A.y;
    part[r][slot * 8 + 2] = A.z; part[r][slot * 8 + 3] = A.w;
    part[r][slot * 8 + 4] = B.x; part[r][slot * 8 + 5] = B.y;
    part[r][slot * 8 + 6] = B.z; part[r][slot * 8 + 7] = B.w;
    __syncthreads();
    if (t < 64) {
        float acc = 0.0f;
        #pragma unroll 8
        for (int rr = 0; rr < 32; ++rr) acc += part[rr][t];
        float c = fmaxf((float)(e - s), 1.0f);
        mean[t] = acc / c;
    }
    __syncthreads();
    if (t < 64) {
        float a = bl1[t];
        #pragma unroll 8
        for (int k = 0; k < 64; ++k) a += mean[k] * Wl1[k * 64 + t];
        hid[t] = fmaxf(a, 0.0f);
    }
    __syncthreads();
    if (t < 2) {
        float o = bl2[t];
        #pragma unroll 8
        for (int k = 0; k < 64; ++k) o += hid[k] * Wl2[k * 2 + t];
        out[g * 2 + t] = o;
    }
}

extern "C" void kernel_launch(void* const* d_in, const int* in_sizes, int n_in,
                              void* d_out, int out_size, void* d_ws, size_t ws_size,
                              hipStream_t stream) {
    const float* x    = (const float*)d_in[0];
    const int*   ei   = (const int*)d_in[1];
    const int*   batch= (const int*)d_in[2];
    const float* W1   = (const float*)d_in[3];
    const float* b1   = (const float*)d_in[4];
    const float* W2   = (const float*)d_in[5];
    const float* b2   = (const float*)d_in[6];
    const float* W3   = (const float*)d_in[7];
    const float* b3   = (const float*)d_in[8];
    const float* Wl1  = (const float*)d_in[9];
    const float* bl1  = (const float*)d_in[10];
    const float* Wl2  = (const float*)d_in[11];
    const float* bl2  = (const float*)d_in[12];
    float* out = (float*)d_out;

    const int n  = in_sizes[2];      // 100000
    const int nE = in_sizes[1] / 2;  // 3200000
    const int* src = ei;
    const int* dst = ei + nE;

    const int NSB   = (n + NPSB - 1) / NPSB;   // 391 super-buckets (256 nodes)
    const int NBLK1 = (nE + EPA1 - 1) / EPA1;  // 391 level-1 blocks
    const int NG    = 1024;
    const int qsz   = (n + 3) / 4;             // src-quartile size
    const unsigned qmagic = (unsigned)((0x100000000ULL + qsz - 1) / qsz);

    char* w = (char*)d_ws;
    auto alloc_f = [&](size_t cnt) { float* p = (float*)w; w += cnt * 4; return p; };
    auto alloc_i = [&](size_t cnt) { int*   p = (int*)w;   w += cnt * 4; return p; };
    auto alloc_h = [&](size_t cnt) { __half* p = (__half*)w; w += cnt * 2; return p; };

    float*    dinv   = alloc_f(n);
    int*      start  = alloc_i(n);
    unsigned* poff   = (unsigned*)alloc_i(n);
    int*      cnt1   = alloc_i((size_t)NBLK1 * PAD1);
    int*      po1    = alloc_i((size_t)NBLK1 * PAD1);
    int*      totals = alloc_i(512);
    unsigned* ebuf   = (unsigned*)alloc_i(nE);   // 12.8 MB
    int*      col    = alloc_i(nE);              // 12.8 MB
    __half* Pd1 = alloc_h((size_t)n * 16);  // 3.2 MB fp16
    __half* h1d = alloc_h((size_t)n * 16);  // 3.2 MB fp16
    __half* h2d = alloc_h((size_t)n * 32);  // 6.4 MB fp16
    __half* h3  = alloc_h((size_t)n * 64);  // 12.8 MB fp16

    const int B = 256;
    auto g = [&](long long t) { return (int)((t + B - 1) / B); };

    // ---- CSR build: two-level radix, zero global atomics
    k_hist1<<<NBLK1, 1024, 0, stream>>>(dst, cnt1, nE, NSB);
    k_scan1<<<NSB, 512, 0, stream>>>(cnt1, po1, totals, NBLK1);
    k_scat1<<<NBLK1, 1024, 0, stream>>>(src, dst, po1, totals, ebuf, nE, NSB);
    k_sort2<<<NSB, 512, 0, stream>>>(ebuf, totals, col, start, dinv, poff, n,
                                     qmagic, NSB);

    // ---- layer 1: Pd1 = dinv*(x@W1) [fp16]; h1d = dinv*relu(dinv*Agg(Pd1)+b1)
    k_mm1<<<(n + 63) / 64, 256, 0, stream>>>((const float4*)x, (const float4*)W1,
                                             dinv, Pd1, n);
    k_aggf16<<<g((long long)n * 4), B, 0, stream>>>((const uint4*)Pd1, start, poff,
                                                    col, dinv, b1, (uint4*)h1d, n);

    // ---- layer 2 (agg + mm2 fused): h2d = dinv*relu((dinv*Agg(h1d))@W2+b2)
    k_aggf16_mm2<<<g((long long)n * 4), B, 0, stream>>>((const uint4*)h1d, start,
                                                        poff, col, dinv, W2, b2,
                                                        (uint4*)h2d, n);

    // ---- layer 3 (agg + mm3 fused): h3 = relu((dinv*Agg(h2d))@W3+b3) [fp16]
    k_aggf32_mm3<<<(int)(((long long)n * 8 + 511) / 512), 512, 0, stream>>>(
        (const uint4*)h2d, start, poff, col, dinv, W3, b3, (uint4*)h3, n);

    // ---- fused mean-pool + head (no atomics; batch is sorted)
    k_poolhead<<<NG, 256, 0, stream>>>((const uint4*)h3, batch, Wl1, bl1, Wl2,
                                       bl2, out, n);
}